// Round 1
// baseline (27790.271 us; speedup 1.0000x reference)
//
#include <hip/hip_runtime.h>
#include <hip/hip_bf16.h>
#include <math.h>

// ---- problem constants ----
#define S_LEN   197
#define NPATCH  196
#define BATCHSZ 32
#define DMODEL  768
#define NHEAD   12
#define HDIM    64
#define FFDIM   3072
#define NLAYER  12
#define NCLS    1000
#define NTOK    (BATCHSZ * S_LEN)   // 6304

#define FLAG_BIAS  1
#define FLAG_RESID 2
#define FLAG_GELU  4

// =====================================================================
// patch extraction: images [32,224,224,3] -> patches [32*196, 768]
// patches[b*196+p, (pi*16+pj)*3+c] = images[b, i*16+pi, j*16+pj, c]
// =====================================================================
__global__ __launch_bounds__(256) void extract_patches_k(
    const float* __restrict__ images, float* __restrict__ patches)
{
    int r = blockIdx.x;              // b*196 + p
    int b = r / NPATCH, p = r - b * NPATCH;
    int i = p / 14, j = p - i * 14;
    int tid = threadIdx.x;
#pragma unroll
    for (int t = 0; t < 3; ++t) {
        int k = tid + t * 256;       // 0..767
        int pi = k / 48;
        int rem = k - pi * 48;
        int pj = rem / 3;
        int c  = rem - pj * 3;
        long long src = (((long long)(b * 224 + i * 16 + pi)) * 224 + (j * 16 + pj)) * 3 + c;
        patches[(long long)r * 768 + k] = images[src];
    }
}

// cls row fill: x[b, 0, :] = cls[:]
__global__ __launch_bounds__(256) void cls_fill_k(
    const float* __restrict__ cls, float* __restrict__ x)
{
    int idx = blockIdx.x * 256 + threadIdx.x;   // 0 .. 32*768-1
    int b = idx / DMODEL, d = idx - b * DMODEL;
    x[(long long)b * S_LEN * DMODEL + d] = cls[d];
}

// =====================================================================
// LayerNorm over last dim (768). One block per row, 256 thr * 3 elems.
// =====================================================================
__global__ __launch_bounds__(256) void ln_k(
    const float* __restrict__ xin, long long instride,
    const float* __restrict__ g, const float* __restrict__ b,
    float* __restrict__ xout, long long outstride)
{
    int row = blockIdx.x;
    const float* xr = xin + (long long)row * instride;
    float* orow = xout + (long long)row * outstride;
    int tid = threadIdx.x;

    float v0 = xr[tid], v1 = xr[tid + 256], v2 = xr[tid + 512];

    __shared__ float s[256];
    // mean
    s[tid] = v0 + v1 + v2;
    __syncthreads();
    for (int st = 128; st > 0; st >>= 1) {
        if (tid < st) s[tid] += s[tid + st];
        __syncthreads();
    }
    float mean = s[0] * (1.0f / DMODEL);
    __syncthreads();
    // var (population)
    float d0 = v0 - mean, d1 = v1 - mean, d2 = v2 - mean;
    s[tid] = d0 * d0 + d1 * d1 + d2 * d2;
    __syncthreads();
    for (int st = 128; st > 0; st >>= 1) {
        if (tid < st) s[tid] += s[tid + st];
        __syncthreads();
    }
    float var = s[0] * (1.0f / DMODEL);
    float rs = rsqrtf(var + 1e-5f);

    orow[tid]       = d0 * rs * g[tid]       + b[tid];
    orow[tid + 256] = d1 * rs * g[tid + 256] + b[tid + 256];
    orow[tid + 512] = d2 * rs * g[tid + 512] + b[tid + 512];
}

// =====================================================================
// fused attention scores + softmax:
// P[z, q, :] = softmax( Q[z,q,:] . K[z,k,:] * 0.125 )   z = b*12+h
// grid (197, 384), 256 threads
// =====================================================================
__global__ __launch_bounds__(256) void attn_softmax_k(
    const float* __restrict__ Q, const float* __restrict__ K,
    float* __restrict__ P)
{
    int q = blockIdx.x;
    int z = blockIdx.y;
    const float* Qrow = Q + ((long long)z * S_LEN + q) * HDIM;
    const float* Kb   = K + (long long)z * S_LEN * HDIM;
    float* Prow       = P + ((long long)z * S_LEN + q) * S_LEN;

    __shared__ float qs[HDIM];
    int tid = threadIdx.x;
    if (tid < HDIM) qs[tid] = Qrow[tid];
    __syncthreads();

    float val = -INFINITY;
    if (tid < S_LEN) {
        const float* Krow = Kb + (long long)tid * HDIM;
        float dot = 0.f;
#pragma unroll
        for (int e = 0; e < HDIM; ++e) dot = fmaf(qs[e], Krow[e], dot);
        val = dot * 0.125f;
    }

    __shared__ float s[256];
    s[tid] = val;
    __syncthreads();
    for (int st = 128; st > 0; st >>= 1) {
        if (tid < st) s[tid] = fmaxf(s[tid], s[tid + st]);
        __syncthreads();
    }
    float mx = s[0];
    __syncthreads();

    float e = (tid < S_LEN) ? expf(val - mx) : 0.f;
    s[tid] = e;
    __syncthreads();
    for (int st = 128; st > 0; st >>= 1) {
        if (tid < st) s[tid] += s[tid + st];
        __syncthreads();
    }
    float inv = 1.0f / s[0];
    if (tid < S_LEN) Prow[tid] = e * inv;
}

// =====================================================================
// generic batched GEMM: C = act(A @ B + bias) + resid
// per batch z: zo = z/innerB, zi = z%innerB; each pointer offset by
// zo*outer_stride + zi*inner_stride.
// 64x64 tile, BK=16, 256 threads, 4x4 per thread, fp32.
// =====================================================================
#define BM 64
#define BN 64
#define BK 16

__global__ __launch_bounds__(256) void gemm_k(
    const float* __restrict__ A, const float* __restrict__ B,
    const float* __restrict__ bias, const float* __restrict__ resid,
    float* __restrict__ C,
    int M, int N, int K,
    int lda, int ldb, int ldc, int ldr,
    int innerB,
    long long sAo, long long sAi, long long sBo, long long sBi,
    long long sCo, long long sCi, long long sbo, long long sbi,
    long long sRo, long long sRi,
    int flags)
{
    int z  = blockIdx.z;
    int zo = z / innerB, zi = z - zo * innerB;
    A += zo * sAo + zi * sAi;
    B += zo * sBo + zi * sBi;
    C += zo * sCo + zi * sCi;
    if (flags & FLAG_BIAS)  bias  += zo * sbo + zi * sbi;
    if (flags & FLAG_RESID) resid += zo * sRo + zi * sRi;

    __shared__ float As[BK][BM + 1];   // +1 pad: kills store bank conflicts
    __shared__ float Bs[BK][BN];

    int tid = threadIdx.x;
    int tx = tid & 15, ty = tid >> 4;          // 16x16 thread grid
    int block_m = blockIdx.y * BM, block_n = blockIdx.x * BN;

    float acc[4][4] = {};

    int nk = (K + BK - 1) / BK;
    for (int kt = 0; kt < nk; ++kt) {
        int k0 = kt * BK;
        // A tile -> As[k][m]   (coalesced on k)
        {
            int kk = tid & 15;
            int mm = tid >> 4;
#pragma unroll
            for (int i = 0; i < 4; ++i) {
                int m = block_m + mm + i * 16;
                int k = k0 + kk;
                float v = 0.f;
                if (m < M && k < K) v = A[(long long)m * lda + k];
                As[kk][mm + i * 16] = v;
            }
        }
        // B tile -> Bs[k][n]   (coalesced on n)
        {
            int nn  = tid & 63;
            int kk4 = tid >> 6;
#pragma unroll
            for (int i = 0; i < 4; ++i) {
                int k = k0 + kk4 + i * 4;
                int n = block_n + nn;
                float v = 0.f;
                if (k < K && n < N) v = B[(long long)k * ldb + n];
                Bs[kk4 + i * 4][nn] = v;
            }
        }
        __syncthreads();
#pragma unroll
        for (int kk = 0; kk < BK; ++kk) {
            float a[4], bb[4];
#pragma unroll
            for (int i = 0; i < 4; ++i) a[i] = As[kk][ty * 4 + i];
#pragma unroll
            for (int j = 0; j < 4; ++j) bb[j] = Bs[kk][tx * 4 + j];
#pragma unroll
            for (int i = 0; i < 4; ++i)
#pragma unroll
                for (int j = 0; j < 4; ++j)
                    acc[i][j] = fmaf(a[i], bb[j], acc[i][j]);
        }
        __syncthreads();
    }

#pragma unroll
    for (int i = 0; i < 4; ++i) {
        int m = block_m + ty * 4 + i;
        if (m >= M) continue;
#pragma unroll
        for (int j = 0; j < 4; ++j) {
            int n = block_n + tx * 4 + j;
            if (n >= N) continue;
            float v = acc[i][j];
            if (flags & FLAG_BIAS) v += bias[n];
            if (flags & FLAG_GELU) v = 0.5f * v * (1.0f + erff(v * 0.70710678118f));
            if (flags & FLAG_RESID) v += resid[(long long)m * ldr + n];
            C[(long long)m * ldc + n] = v;
        }
    }
}

static inline void launch_gemm(hipStream_t stream,
    const float* A, const float* B, const float* bias, const float* resid, float* C,
    int M, int N, int K, int lda, int ldb, int ldc, int ldr,
    int batch, int innerB,
    long long sAo, long long sAi, long long sBo, long long sBi,
    long long sCo, long long sCi, long long sbo, long long sbi,
    long long sRo, long long sRi, int flags)
{
    dim3 grid((N + BN - 1) / BN, (M + BM - 1) / BM, batch);
    gemm_k<<<grid, dim3(256), 0, stream>>>(A, B, bias, resid, C, M, N, K,
        lda, ldb, ldc, ldr, innerB, sAo, sAi, sBo, sBi, sCo, sCi, sbo, sbi, sRo, sRi, flags);
}

extern "C" void kernel_launch(void* const* d_in, const int* in_sizes, int n_in,
                              void* d_out, int out_size, void* d_ws, size_t ws_size,
                              hipStream_t stream)
{
    const float* images   = (const float*)d_in[0];
    const float* patch_W  = (const float*)d_in[1];
    const float* patch_b  = (const float*)d_in[2];
    const float* pos_emb  = (const float*)d_in[3];
    const float* cls      = (const float*)d_in[4];
    const float* ln1_g    = (const float*)d_in[5];
    const float* ln1_b    = (const float*)d_in[6];
    const float* Wq       = (const float*)d_in[7];
    const float* bq       = (const float*)d_in[8];
    const float* Wk       = (const float*)d_in[9];
    const float* bk       = (const float*)d_in[10];
    const float* Wv       = (const float*)d_in[11];
    const float* bv       = (const float*)d_in[12];
    const float* Wo       = (const float*)d_in[13];
    const float* bo       = (const float*)d_in[14];
    const float* ln2_g    = (const float*)d_in[15];
    const float* ln2_b    = (const float*)d_in[16];
    const float* W1       = (const float*)d_in[17];
    const float* b1       = (const float*)d_in[18];
    const float* W2       = (const float*)d_in[19];
    const float* b2       = (const float*)d_in[20];
    const float* head_g   = (const float*)d_in[21];
    const float* head_bn  = (const float*)d_in[22];
    const float* head_W   = (const float*)d_in[23];
    const float* head_bias= (const float*)d_in[24];
    float* out = (float*)d_out;

    float* ws = (float*)d_ws;
    const long long SZ = (long long)NTOK * DMODEL;          // 4,841,472
    float* x    = ws;                                        // [6304,768]
    float* xn   = ws + SZ;                                   // [6304,768]
    float* Qb   = ws + 2 * SZ;                               // [384,197,64]
    float* Kb   = ws + 3 * SZ;
    float* Vb   = ws + 4 * SZ;
    float* Pb   = ws + 5 * SZ;                               // [384,197,197] (union h1)
    float* h1   = Pb;                                        // [6304,3072]
    float* Ob   = ws + 5 * SZ + (long long)NTOK * FFDIM;     // [6304,768] (union patches)
    float* patches = Ob;                                     // [6272,768]
    float* xcls = Ob + SZ;                                   // [32,768]

    // ---- embed ----
    extract_patches_k<<<dim3(BATCHSZ * NPATCH), dim3(256), 0, stream>>>(images, patches);
    cls_fill_k<<<dim3(BATCHSZ * DMODEL / 256), dim3(256), 0, stream>>>(cls, x);
    // x[b, 1+p, :] = patches[b,p,:] @ patch_W + patch_b + pos_emb[p,:]
    launch_gemm(stream, patches, patch_W, patch_b, pos_emb, x + DMODEL,
                NPATCH, DMODEL, 768, 768, DMODEL, DMODEL, DMODEL,
                BATCHSZ, 1,
                (long long)NPATCH * 768, 0, 0, 0,
                (long long)S_LEN * DMODEL, 0, 0, 0, 0, 0,
                FLAG_BIAS | FLAG_RESID);

    const long long WQKV_L = (long long)NHEAD * DMODEL * HDIM;  // per-layer qkv weight
    for (int l = 0; l < NLAYER; ++l) {
        // ln1
        ln_k<<<dim3(NTOK), dim3(256), 0, stream>>>(x, DMODEL, ln1_g + l * DMODEL, ln1_b + l * DMODEL, xn, DMODEL);

        // Q/K/V : per (b,h) GEMM [197,768]x[768,64], z = b*12+h
        const float* Wqkv[3] = { Wq + (long long)l * WQKV_L, Wk + (long long)l * WQKV_L, Wv + (long long)l * WQKV_L };
        const float* bqkv[3] = { bq + (long long)l * NHEAD * HDIM, bk + (long long)l * NHEAD * HDIM, bv + (long long)l * NHEAD * HDIM };
        float* dsts[3] = { Qb, Kb, Vb };
        for (int t = 0; t < 3; ++t) {
            launch_gemm(stream, xn, Wqkv[t], bqkv[t], nullptr, dsts[t],
                        S_LEN, HDIM, DMODEL, DMODEL, HDIM, HDIM, 0,
                        BATCHSZ * NHEAD, NHEAD,
                        (long long)S_LEN * DMODEL, 0,              // A: per-b
                        0, (long long)DMODEL * HDIM,               // B: per-h
                        (long long)NHEAD * S_LEN * HDIM, (long long)S_LEN * HDIM, // C
                        0, (long long)HDIM,                        // bias per-h
                        0, 0, FLAG_BIAS);
        }

        // scores + softmax
        attn_softmax_k<<<dim3(S_LEN, BATCHSZ * NHEAD), dim3(256), 0, stream>>>(Qb, Kb, Pb);

        // O[b, q, h*64+e] = P[z] @ V[z]
        launch_gemm(stream, Pb, Vb, nullptr, nullptr, Ob,
                    S_LEN, HDIM, S_LEN, S_LEN, HDIM, DMODEL, 0,
                    BATCHSZ * NHEAD, NHEAD,
                    (long long)NHEAD * S_LEN * S_LEN, (long long)S_LEN * S_LEN,
                    (long long)NHEAD * S_LEN * HDIM, (long long)S_LEN * HDIM,
                    (long long)S_LEN * DMODEL, (long long)HDIM,
                    0, 0, 0, 0, 0);

        // x += O @ Wo + bo
        launch_gemm(stream, Ob, Wo + (long long)l * DMODEL * DMODEL, bo + l * DMODEL, x, x,
                    NTOK, DMODEL, DMODEL, DMODEL, DMODEL, DMODEL, DMODEL,
                    1, 1, 0, 0, 0, 0, 0, 0, 0, 0, 0, 0,
                    FLAG_BIAS | FLAG_RESID);

        // ln2
        ln_k<<<dim3(NTOK), dim3(256), 0, stream>>>(x, DMODEL, ln2_g + l * DMODEL, ln2_b + l * DMODEL, xn, DMODEL);

        // h1 = gelu(xn @ W1 + b1)
        launch_gemm(stream, xn, W1 + (long long)l * DMODEL * FFDIM, b1 + (long long)l * FFDIM, nullptr, h1,
                    NTOK, FFDIM, DMODEL, DMODEL, FFDIM, FFDIM, 0,
                    1, 1, 0, 0, 0, 0, 0, 0, 0, 0, 0, 0,
                    FLAG_BIAS | FLAG_GELU);

        // x += h1 @ W2 + b2
        launch_gemm(stream, h1, W2 + (long long)l * FFDIM * DMODEL, b2 + l * DMODEL, x, x,
                    NTOK, DMODEL, FFDIM, FFDIM, DMODEL, DMODEL, DMODEL,
                    1, 1, 0, 0, 0, 0, 0, 0, 0, 0, 0, 0,
                    FLAG_BIAS | FLAG_RESID);
    }

    // ---- head ----
    ln_k<<<dim3(BATCHSZ), dim3(256), 0, stream>>>(x, (long long)S_LEN * DMODEL, head_g, head_bn, xcls, DMODEL);
    launch_gemm(stream, xcls, head_W, head_bias, nullptr, out,
                BATCHSZ, NCLS, DMODEL, DMODEL, NCLS, NCLS, 0,
                1, 1, 0, 0, 0, 0, 0, 0, 0, 0, 0, 0,
                FLAG_BIAS);
}

// Round 2
// 11316.763 us; speedup vs baseline: 2.4557x; 2.4557x over previous
//
#include <hip/hip_runtime.h>
#include <hip/hip_bf16.h>
#include <math.h>

// ---- problem constants ----
#define S_LEN   197
#define NPATCH  196
#define BATCHSZ 32
#define DMODEL  768
#define NHEAD   12
#define HDIM    64
#define FFDIM   3072
#define NLAYER  12
#define NCLS    1000
#define NTOK    (BATCHSZ * S_LEN)   // 6304

#define FLAG_BIAS    1
#define FLAG_RESID   2
#define FLAG_GELU    4
#define FLAG_OUTBF16 8

typedef __attribute__((ext_vector_type(8))) short short8;
typedef __attribute__((ext_vector_type(4))) float f32x4;
typedef __hip_bfloat16 bf16;

#define GLOBAL_AS __attribute__((address_space(1)))
#define LDS_AS    __attribute__((address_space(3)))

// =====================================================================
// patch extraction -> bf16 patches [32*196, 768]
// =====================================================================
__global__ __launch_bounds__(256) void extract_patches_k(
    const float* __restrict__ images, bf16* __restrict__ patches)
{
    int r = blockIdx.x;              // b*196 + p
    int b = r / NPATCH, p = r - b * NPATCH;
    int i = p / 14, j = p - i * 14;
    int tid = threadIdx.x;
#pragma unroll
    for (int t = 0; t < 3; ++t) {
        int k = tid + t * 256;       // 0..767
        int pi = k / 48;
        int rem = k - pi * 48;
        int pj = rem / 3;
        int c  = rem - pj * 3;
        long long src = (((long long)(b * 224 + i * 16 + pi)) * 224 + (j * 16 + pj)) * 3 + c;
        patches[(long long)r * 768 + k] = __float2bfloat16(images[src]);
    }
}

// cls row fill: x[b, 0, :] = cls[:]
__global__ __launch_bounds__(256) void cls_fill_k(
    const float* __restrict__ cls, float* __restrict__ x)
{
    int idx = blockIdx.x * 256 + threadIdx.x;   // 0 .. 32*768-1
    int b = idx / DMODEL, d = idx - b * DMODEL;
    x[(long long)b * S_LEN * DMODEL + d] = cls[d];
}

// x[b, 1+p, :] = ptmp[b*196+p, :] + pos_emb[p, :]
__global__ __launch_bounds__(256) void add_pos_k(
    const float* __restrict__ ptmp, const float* __restrict__ pos,
    float* __restrict__ x)
{
    long long idx = (long long)blockIdx.x * 256 + threadIdx.x;  // 0..6272*768-1
    int r = idx / DMODEL, d = idx - (long long)r * DMODEL;
    int b = r / NPATCH, p = r - b * NPATCH;
    x[((long long)b * S_LEN + 1 + p) * DMODEL + d] = ptmp[idx] + pos[(long long)p * DMODEL + d];
}

// pack per-layer qkv bias into [2304]
__global__ __launch_bounds__(256) void pack_bqkv_k(
    const float* __restrict__ bq, const float* __restrict__ bk,
    const float* __restrict__ bv, float* __restrict__ dst)
{
    int n = blockIdx.x * 256 + threadIdx.x;     // 0..2303
    int t = n / 768, r = n - t * 768;
    const float* s = (t == 0) ? bq : (t == 1) ? bk : bv;
    dst[n] = s[r];
}

// =====================================================================
// tiled transpose + fp32->bf16 convert: src [R][C] -> dst [C][R]
// grid: (ceil(C/32), ceil(R/32), batch)
// =====================================================================
__global__ __launch_bounds__(256) void transpose_conv_k(
    const float* __restrict__ src, bf16* __restrict__ dst,
    int R, int C, long long sstride, long long dstride)
{
    src += (long long)blockIdx.z * sstride;
    dst += (long long)blockIdx.z * dstride;
    __shared__ float t[32][33];
    int tx = threadIdx.x & 31, ty = threadIdx.x >> 5;   // ty 0..7
    int c0 = blockIdx.x * 32, r0 = blockIdx.y * 32;
#pragma unroll
    for (int i = 0; i < 4; ++i) {
        int r = r0 + ty + i * 8;
        if (r < R && c0 + tx < C) t[ty + i * 8][tx] = src[(long long)r * C + c0 + tx];
    }
    __syncthreads();
#pragma unroll
    for (int i = 0; i < 4; ++i) {
        int c = c0 + ty + i * 8;
        if (c < C && r0 + tx < R) dst[(long long)c * R + r0 + tx] = __float2bfloat16(t[tx][ty + i * 8]);
    }
}

// =====================================================================
// LayerNorm over last dim (768). fp32 out and bf16 out variants.
// =====================================================================
__global__ __launch_bounds__(256) void ln_k(
    const float* __restrict__ xin, long long instride,
    const float* __restrict__ g, const float* __restrict__ b,
    float* __restrict__ xout, long long outstride)
{
    int row = blockIdx.x;
    const float* xr = xin + (long long)row * instride;
    float* orow = xout + (long long)row * outstride;
    int tid = threadIdx.x;
    float v0 = xr[tid], v1 = xr[tid + 256], v2 = xr[tid + 512];
    __shared__ float s[256];
    s[tid] = v0 + v1 + v2;
    __syncthreads();
    for (int st = 128; st > 0; st >>= 1) { if (tid < st) s[tid] += s[tid + st]; __syncthreads(); }
    float mean = s[0] * (1.0f / DMODEL);
    __syncthreads();
    float d0 = v0 - mean, d1 = v1 - mean, d2 = v2 - mean;
    s[tid] = d0 * d0 + d1 * d1 + d2 * d2;
    __syncthreads();
    for (int st = 128; st > 0; st >>= 1) { if (tid < st) s[tid] += s[tid + st]; __syncthreads(); }
    float rs = rsqrtf(s[0] * (1.0f / DMODEL) + 1e-5f);
    orow[tid]       = d0 * rs * g[tid]       + b[tid];
    orow[tid + 256] = d1 * rs * g[tid + 256] + b[tid + 256];
    orow[tid + 512] = d2 * rs * g[tid + 512] + b[tid + 512];
}

__global__ __launch_bounds__(256) void ln_bf_k(
    const float* __restrict__ xin, long long instride,
    const float* __restrict__ g, const float* __restrict__ b,
    bf16* __restrict__ xout, long long outstride)
{
    int row = blockIdx.x;
    const float* xr = xin + (long long)row * instride;
    bf16* orow = xout + (long long)row * outstride;
    int tid = threadIdx.x;
    float v0 = xr[tid], v1 = xr[tid + 256], v2 = xr[tid + 512];
    __shared__ float s[256];
    s[tid] = v0 + v1 + v2;
    __syncthreads();
    for (int st = 128; st > 0; st >>= 1) { if (tid < st) s[tid] += s[tid + st]; __syncthreads(); }
    float mean = s[0] * (1.0f / DMODEL);
    __syncthreads();
    float d0 = v0 - mean, d1 = v1 - mean, d2 = v2 - mean;
    s[tid] = d0 * d0 + d1 * d1 + d2 * d2;
    __syncthreads();
    for (int st = 128; st > 0; st >>= 1) { if (tid < st) s[tid] += s[tid + st]; __syncthreads(); }
    float rs = rsqrtf(s[0] * (1.0f / DMODEL) + 1e-5f);
    orow[tid]       = __float2bfloat16(d0 * rs * g[tid]       + b[tid]);
    orow[tid + 256] = __float2bfloat16(d1 * rs * g[tid + 256] + b[tid + 256]);
    orow[tid + 512] = __float2bfloat16(d2 * rs * g[tid + 512] + b[tid + 512]);
}

// =====================================================================
// fused attention scores + softmax (fp32), qkv packed layout:
// Q(b,s,h,e) = qkv[(b*197+s)*2304 + h*64 + e]; K at +768
// grid (197, 384), 256 threads
// =====================================================================
__global__ __launch_bounds__(256) void attn_softmax_k(
    const float* __restrict__ qkv, float* __restrict__ P)
{
    int q = blockIdx.x;
    int z = blockIdx.y;
    int b = z / NHEAD, h = z - b * NHEAD;
    const float* Qrow = qkv + ((long long)(b * S_LEN + q)) * 2304 + h * HDIM;
    const float* Kb   = qkv + (long long)b * S_LEN * 2304 + 768 + h * HDIM;
    float* Prow       = P + ((long long)z * S_LEN + q) * S_LEN;

    __shared__ float qs[HDIM];
    int tid = threadIdx.x;
    if (tid < HDIM) qs[tid] = Qrow[tid];
    __syncthreads();

    float val = -INFINITY;
    if (tid < S_LEN) {
        const float* Krow = Kb + (long long)tid * 2304;
        float dot = 0.f;
#pragma unroll
        for (int e = 0; e < HDIM; ++e) dot = fmaf(qs[e], Krow[e], dot);
        val = dot * 0.125f;
    }
    __shared__ float s[256];
    s[tid] = val;
    __syncthreads();
    for (int st = 128; st > 0; st >>= 1) { if (tid < st) s[tid] = fmaxf(s[tid], s[tid + st]); __syncthreads(); }
    float mx = s[0];
    __syncthreads();
    float e = (tid < S_LEN) ? expf(val - mx) : 0.f;
    s[tid] = e;
    __syncthreads();
    for (int st = 128; st > 0; st >>= 1) { if (tid < st) s[tid] += s[tid + st]; __syncthreads(); }
    float inv = 1.0f / s[0];
    if (tid < S_LEN) Prow[tid] = e * inv;
}

// =====================================================================
// fp32 batched GEMM (kept for PV + head). 64x64 tile, BK=16.
// =====================================================================
#define BM 64
#define BN 64
#define BK 16

__global__ __launch_bounds__(256) void gemm_k(
    const float* __restrict__ A, const float* __restrict__ B,
    const float* __restrict__ bias, const float* __restrict__ resid,
    float* __restrict__ C, bf16* __restrict__ Cb,
    int M, int N, int K,
    int lda, int ldb, int ldc, int ldr,
    int innerB,
    long long sAo, long long sAi, long long sBo, long long sBi,
    long long sCo, long long sCi, long long sbo, long long sbi,
    long long sRo, long long sRi,
    int flags)
{
    int z  = blockIdx.z;
    int zo = z / innerB, zi = z - zo * innerB;
    A += zo * sAo + zi * sAi;
    B += zo * sBo + zi * sBi;
    if (C)  C  += zo * sCo + zi * sCi;
    if (Cb) Cb += zo * sCo + zi * sCi;
    if (flags & FLAG_BIAS)  bias  += zo * sbo + zi * sbi;
    if (flags & FLAG_RESID) resid += zo * sRo + zi * sRi;

    __shared__ float As[BK][BM + 1];
    __shared__ float Bs[BK][BN];

    int tid = threadIdx.x;
    int tx = tid & 15, ty = tid >> 4;
    int block_m = blockIdx.y * BM, block_n = blockIdx.x * BN;

    float acc[4][4] = {};
    int nk = (K + BK - 1) / BK;
    for (int kt = 0; kt < nk; ++kt) {
        int k0 = kt * BK;
        {
            int kk = tid & 15, mm = tid >> 4;
#pragma unroll
            for (int i = 0; i < 4; ++i) {
                int m = block_m + mm + i * 16, k = k0 + kk;
                float v = 0.f;
                if (m < M && k < K) v = A[(long long)m * lda + k];
                As[kk][mm + i * 16] = v;
            }
        }
        {
            int nn = tid & 63, kk4 = tid >> 6;
#pragma unroll
            for (int i = 0; i < 4; ++i) {
                int k = k0 + kk4 + i * 4, n = block_n + nn;
                float v = 0.f;
                if (k < K && n < N) v = B[(long long)k * ldb + n];
                Bs[kk4 + i * 4][nn] = v;
            }
        }
        __syncthreads();
#pragma unroll
        for (int kk = 0; kk < BK; ++kk) {
            float a[4], bb[4];
#pragma unroll
            for (int i = 0; i < 4; ++i) a[i] = As[kk][ty * 4 + i];
#pragma unroll
            for (int j = 0; j < 4; ++j) bb[j] = Bs[kk][tx * 4 + j];
#pragma unroll
            for (int i = 0; i < 4; ++i)
#pragma unroll
                for (int j = 0; j < 4; ++j)
                    acc[i][j] = fmaf(a[i], bb[j], acc[i][j]);
        }
        __syncthreads();
    }
#pragma unroll
    for (int i = 0; i < 4; ++i) {
        int m = block_m + ty * 4 + i;
        if (m >= M) continue;
#pragma unroll
        for (int j = 0; j < 4; ++j) {
            int n = block_n + tx * 4 + j;
            if (n >= N) continue;
            float v = acc[i][j];
            if (flags & FLAG_BIAS) v += bias[n];
            if (flags & FLAG_GELU) v = 0.5f * v * (1.0f + erff(v * 0.70710678118f));
            if (flags & FLAG_RESID) v += resid[(long long)m * ldr + n];
            if (flags & FLAG_OUTBF16) Cb[(long long)m * ldc + n] = __float2bfloat16(v);
            else C[(long long)m * ldc + n] = v;
        }
    }
}

static inline void launch_gemm(hipStream_t stream,
    const float* A, const float* B, const float* bias, const float* resid,
    float* C, bf16* Cb,
    int M, int N, int K, int lda, int ldb, int ldc, int ldr,
    int batch, int innerB,
    long long sAo, long long sAi, long long sBo, long long sBi,
    long long sCo, long long sCi, long long sbo, long long sbi,
    long long sRo, long long sRi, int flags)
{
    dim3 grid((N + BN - 1) / BN, (M + BM - 1) / BM, batch);
    gemm_k<<<grid, dim3(256), 0, stream>>>(A, B, bias, resid, C, Cb, M, N, K,
        lda, ldb, ldc, ldr, innerB, sAo, sAi, sBo, sBi, sCo, sCi, sbo, sbi, sRo, sRi, flags);
}

// =====================================================================
// bf16 MFMA GEMM (m97 structure): C = act(A @ Bt^T + bias) + resid
// A: [M][K] bf16 row-major. Bt: [N][K] bf16 (pre-transposed weights).
// 128x128 tile, BK=32, 256 thr = 4 waves, each wave 64x64 via 4x4 MFMAs.
// LDS is fragment-block ordered so global_load_lds lane order == MFMA
// fragment order: block t (16 rows x 32 k) stored as lane-major 16B units.
// =====================================================================
__global__ __launch_bounds__(256) void mfma_gemm_k(
    const bf16* __restrict__ A, const bf16* __restrict__ Bt,
    const float* __restrict__ bias, const float* __restrict__ resid,
    float* __restrict__ Cf, bf16* __restrict__ Cb,
    int M, int N, int K, int ldc, int ldr, int flags)
{
    __shared__ short As[4096];   // 8 blocks x 512 shorts (1 KB each)
    __shared__ short Bs[4096];

    int tid = threadIdx.x;
    int lane = tid & 63, wid = tid >> 6;
    int wm = wid & 1, wn = wid >> 1;
    long long block_m = (long long)blockIdx.y * 128;
    long long block_n = (long long)blockIdx.x * 128;

    const short* Ag = (const short*)A;
    const short* Bg = (const short*)Bt;

    int rl   = lane & 15;        // row within 16-row block
    int koff = (lane >> 4) * 8;  // k offset within BK=32

    f32x4 acc[4][4] = {};

    for (int k0 = 0; k0 < K; k0 += 32) {
#pragma unroll
        for (int c = 0; c < 4; ++c) {
            int bi = wid * 4 + c;            // 0..15
            int rloc = (bi & 7) * 16 + rl;
            const short* src;
            short* dst;
            if (bi < 8) {
                long long grow = block_m + rloc;
                if (grow >= M) grow = M - 1;          // clamp (stores masked later)
                src = Ag + grow * K + k0 + koff;
                dst = &As[bi * 512];
            } else {
                long long grow = block_n + rloc;      // N is multiple of 128
                src = Bg + grow * K + k0 + koff;
                dst = &Bs[(bi - 8) * 512];
            }
            __builtin_amdgcn_global_load_lds((GLOBAL_AS const void*)src,
                                             (LDS_AS void*)dst, 16, 0, 0);
        }
        __syncthreads();

        short8 a[4], b[4];
        const short8* ap = (const short8*)As;
        const short8* bp = (const short8*)Bs;
#pragma unroll
        for (int i = 0; i < 4; ++i) a[i] = ap[(wm * 4 + i) * 64 + lane];
#pragma unroll
        for (int j = 0; j < 4; ++j) b[j] = bp[(wn * 4 + j) * 64 + lane];
#pragma unroll
        for (int i = 0; i < 4; ++i)
#pragma unroll
            for (int j = 0; j < 4; ++j)
                acc[i][j] = __builtin_amdgcn_mfma_f32_16x16x32_bf16(a[i], b[j], acc[i][j], 0, 0, 0);
        __syncthreads();
    }

    // epilogue: C/D layout col=lane&15, row=(lane>>4)*4+reg
    int cl = lane & 15;
    int rq = (lane >> 4) * 4;
#pragma unroll
    for (int j = 0; j < 4; ++j) {
        long long col = block_n + wn * 64 + j * 16 + cl;
        float bv = (flags & FLAG_BIAS) ? bias[col] : 0.f;
#pragma unroll
        for (int i = 0; i < 4; ++i) {
#pragma unroll
            for (int r = 0; r < 4; ++r) {
                long long row = block_m + wm * 64 + i * 16 + rq + r;
                if (row >= M) continue;
                float v = acc[i][j][r] + bv;
                if (flags & FLAG_GELU) v = 0.5f * v * (1.0f + erff(v * 0.70710678118f));
                if (flags & FLAG_RESID) v += resid[row * (long long)ldr + col];
                if (flags & FLAG_OUTBF16) Cb[row * (long long)ldc + col] = __float2bfloat16(v);
                else Cf[row * (long long)ldc + col] = v;
            }
        }
    }
}

static inline void launch_mfma(hipStream_t stream,
    const bf16* A, const bf16* Bt, const float* bias, const float* resid,
    float* Cf, bf16* Cb, int M, int N, int K, int ldc, int ldr, int flags)
{
    dim3 grid(N / 128, (M + 127) / 128);
    mfma_gemm_k<<<grid, dim3(256), 0, stream>>>(A, Bt, bias, resid, Cf, Cb, M, N, K, ldc, ldr, flags);
}

extern "C" void kernel_launch(void* const* d_in, const int* in_sizes, int n_in,
                              void* d_out, int out_size, void* d_ws, size_t ws_size,
                              hipStream_t stream)
{
    const float* images   = (const float*)d_in[0];
    const float* patch_W  = (const float*)d_in[1];
    const float* patch_b  = (const float*)d_in[2];
    const float* pos_emb  = (const float*)d_in[3];
    const float* cls      = (const float*)d_in[4];
    const float* ln1_g    = (const float*)d_in[5];
    const float* ln1_b    = (const float*)d_in[6];
    const float* Wq       = (const float*)d_in[7];
    const float* bq       = (const float*)d_in[8];
    const float* Wk       = (const float*)d_in[9];
    const float* bk       = (const float*)d_in[10];
    const float* Wv       = (const float*)d_in[11];
    const float* bv       = (const float*)d_in[12];
    const float* Wo       = (const float*)d_in[13];
    const float* bo       = (const float*)d_in[14];
    const float* ln2_g    = (const float*)d_in[15];
    const float* ln2_b    = (const float*)d_in[16];
    const float* W1       = (const float*)d_in[17];
    const float* b1       = (const float*)d_in[18];
    const float* W2       = (const float*)d_in[19];
    const float* b2       = (const float*)d_in[20];
    const float* head_g   = (const float*)d_in[21];
    const float* head_bn  = (const float*)d_in[22];
    const float* head_W   = (const float*)d_in[23];
    const float* head_bias= (const float*)d_in[24];
    float* out = (float*)d_out;

    // ---- workspace carve-up (bytes) ----
    char* p = (char*)d_ws;
    auto alloc = [&](long long nbytes) { char* r = p; p += (nbytes + 255) & ~255LL; return r; };
    const long long SZ = (long long)NTOK * DMODEL;                 // 4,841,472 elems

    float* x      = (float*)alloc(SZ * 4);                          // residual stream fp32
    bf16*  xn     = (bf16*) alloc(SZ * 2);                          // LN output bf16
    float* qkv    = (float*)alloc((long long)NTOK * 2304 * 4);      // fused qkv out (union ptmp)
    float* ptmp   = qkv;                                            // patch gemm out [6272,768]
    float* Pb     = (float*)alloc((long long)BATCHSZ * NHEAD * S_LEN * S_LEN * 4); // union h1
    bf16*  h1     = (bf16*)Pb;                                      // [6304,3072] bf16
    bf16*  Ob     = (bf16*) alloc(SZ * 2);                          // attn out bf16 (union patches)
    bf16*  patches= Ob;                                             // [6272,768] bf16
    bf16*  wqkv_t = (bf16*) alloc((long long)2304 * 768 * 2);       // per-layer converted weights
    bf16*  wo_t   = (bf16*) alloc((long long)768 * 768 * 2);
    bf16*  w1_t   = (bf16*) alloc((long long)3072 * 768 * 2);
    bf16*  w2_t   = (bf16*) alloc((long long)768 * 3072 * 2);
    bf16*  pw_t   = (bf16*) alloc((long long)768 * 768 * 2);
    float* bqkv   = (float*)alloc(2304 * 4);
    float* xcls   = (float*)alloc((long long)BATCHSZ * DMODEL * 4);

    // ---- embed ----
    extract_patches_k<<<dim3(BATCHSZ * NPATCH), dim3(256), 0, stream>>>(images, patches);
    transpose_conv_k<<<dim3(24, 24, 1), dim3(256), 0, stream>>>(patch_W, pw_t, 768, 768, 0, 0);
    launch_mfma(stream, patches, pw_t, patch_b, nullptr, ptmp, nullptr,
                BATCHSZ * NPATCH, DMODEL, 768, DMODEL, 0, FLAG_BIAS);
    cls_fill_k<<<dim3(BATCHSZ * DMODEL / 256), dim3(256), 0, stream>>>(cls, x);
    add_pos_k<<<dim3((BATCHSZ * NPATCH * DMODEL) / 256), dim3(256), 0, stream>>>(ptmp, pos_emb, x);

    const long long WQKV_L = (long long)NHEAD * DMODEL * HDIM;
    for (int l = 0; l < NLAYER; ++l) {
        // ---- convert this layer's weights to bf16 [N][K] ----
        for (int t = 0; t < 3; ++t) {
            const float* Wsrc = (t == 0 ? Wq : t == 1 ? Wk : Wv) + (long long)l * WQKV_L;
            transpose_conv_k<<<dim3(2, 24, NHEAD), dim3(256), 0, stream>>>(
                Wsrc, wqkv_t + (long long)t * 768 * 768,
                DMODEL, HDIM, (long long)DMODEL * HDIM, (long long)HDIM * DMODEL);
        }
        pack_bqkv_k<<<dim3(9), dim3(256), 0, stream>>>(
            bq + (long long)l * 768, bk + (long long)l * 768, bv + (long long)l * 768, bqkv);
        transpose_conv_k<<<dim3(24, 24, 1), dim3(256), 0, stream>>>(
            Wo + (long long)l * DMODEL * DMODEL, wo_t, DMODEL, DMODEL, 0, 0);
        transpose_conv_k<<<dim3(96, 24, 1), dim3(256), 0, stream>>>(
            W1 + (long long)l * DMODEL * FFDIM, w1_t, DMODEL, FFDIM, 0, 0);
        transpose_conv_k<<<dim3(24, 96, 1), dim3(256), 0, stream>>>(
            W2 + (long long)l * FFDIM * DMODEL, w2_t, FFDIM, DMODEL, 0, 0);

        // ---- ln1 -> bf16 ----
        ln_bf_k<<<dim3(NTOK), dim3(256), 0, stream>>>(
            x, DMODEL, ln1_g + l * DMODEL, ln1_b + l * DMODEL, xn, DMODEL);

        // ---- fused QKV: [6304,768] @ [768,2304] -> qkv fp32 ----
        launch_mfma(stream, xn, wqkv_t, bqkv, nullptr, qkv, nullptr,
                    NTOK, 2304, DMODEL, 2304, 0, FLAG_BIAS);

        // ---- scores + softmax (fp32) ----
        attn_softmax_k<<<dim3(S_LEN, BATCHSZ * NHEAD), dim3(256), 0, stream>>>(qkv, Pb);

        // ---- PV: P[z] @ V[z] -> Ob bf16 [b,q,h*64+e] ----
        launch_gemm(stream, Pb, qkv + 2 * 768, nullptr, nullptr, nullptr, Ob,
                    S_LEN, HDIM, S_LEN, S_LEN, 2304, DMODEL, 0,
                    BATCHSZ * NHEAD, NHEAD,
                    (long long)NHEAD * S_LEN * S_LEN, (long long)S_LEN * S_LEN,
                    (long long)S_LEN * 2304, (long long)HDIM,
                    (long long)S_LEN * DMODEL, (long long)HDIM,
                    0, 0, 0, 0, FLAG_OUTBF16);

        // ---- x += Ob @ Wo + bo ----
        launch_mfma(stream, Ob, wo_t, bo + (long long)l * DMODEL, x, x, nullptr,
                    NTOK, DMODEL, DMODEL, DMODEL, DMODEL, FLAG_BIAS | FLAG_RESID);

        // ---- ln2 -> bf16 ----
        ln_bf_k<<<dim3(NTOK), dim3(256), 0, stream>>>(
            x, DMODEL, ln2_g + l * DMODEL, ln2_b + l * DMODEL, xn, DMODEL);

        // ---- h1 = gelu(xn @ W1 + b1) -> bf16 ----
        launch_mfma(stream, xn, w1_t, b1 + (long long)l * FFDIM, nullptr, nullptr, h1,
                    NTOK, FFDIM, DMODEL, FFDIM, 0, FLAG_BIAS | FLAG_GELU | FLAG_OUTBF16);

        // ---- x += h1 @ W2 + b2 ----
        launch_mfma(stream, h1, w2_t, b2 + (long long)l * DMODEL, x, x, nullptr,
                    NTOK, DMODEL, FFDIM, DMODEL, DMODEL, FLAG_BIAS | FLAG_RESID);
    }

    // ---- head (fp32) ----
    ln_k<<<dim3(BATCHSZ), dim3(256), 0, stream>>>(
        x, (long long)S_LEN * DMODEL, head_g, head_bn, xcls, DMODEL);
    launch_gemm(stream, xcls, head_W, head_bias, nullptr, out, nullptr,
                BATCHSZ, NCLS, DMODEL, DMODEL, NCLS, NCLS, 0,
                1, 1, 0, 0, 0, 0, 0, 0, 0, 0, 0, 0,
                FLAG_BIAS);
}

// Round 3
// 5539.043 us; speedup vs baseline: 5.0172x; 2.0431x over previous
//
#include <hip/hip_runtime.h>
#include <hip/hip_bf16.h>
#include <math.h>

// ---- problem constants ----
#define S_LEN   197
#define NPATCH  196
#define BATCHSZ 32
#define DMODEL  768
#define NHEAD   12
#define HDIM    64
#define FFDIM   3072
#define NLAYER  12
#define NCLS    1000
#define NTOK    (BATCHSZ * S_LEN)   // 6304

#define FLAG_BIAS    1
#define FLAG_RESID   2
#define FLAG_GELU    4
#define FLAG_OUTBF16 8

typedef __attribute__((ext_vector_type(8))) short short8;
typedef __attribute__((ext_vector_type(4))) float f32x4;
typedef __hip_bfloat16 bf16;

#define GLOBAL_AS __attribute__((address_space(1)))
#define LDS_AS    __attribute__((address_space(3)))

static __device__ __forceinline__ short bf16bits(float x) {
    bf16 b = __float2bfloat16(x);
    return *reinterpret_cast<short*>(&b);
}

// =====================================================================
// patch extraction -> bf16 patches [32*196, 768]
// =====================================================================
__global__ __launch_bounds__(256) void extract_patches_k(
    const float* __restrict__ images, bf16* __restrict__ patches)
{
    int r = blockIdx.x;              // b*196 + p
    int b = r / NPATCH, p = r - b * NPATCH;
    int i = p / 14, j = p - i * 14;
    int tid = threadIdx.x;
#pragma unroll
    for (int t = 0; t < 3; ++t) {
        int k = tid + t * 256;       // 0..767
        int pi = k / 48;
        int rem = k - pi * 48;
        int pj = rem / 3;
        int c  = rem - pj * 3;
        long long src = (((long long)(b * 224 + i * 16 + pi)) * 224 + (j * 16 + pj)) * 3 + c;
        patches[(long long)r * 768 + k] = __float2bfloat16(images[src]);
    }
}

// cls row fill: x[b, 0, :] = cls[:]
__global__ __launch_bounds__(256) void cls_fill_k(
    const float* __restrict__ cls, float* __restrict__ x)
{
    int idx = blockIdx.x * 256 + threadIdx.x;   // 0 .. 32*768-1
    int b = idx / DMODEL, d = idx - b * DMODEL;
    x[(long long)b * S_LEN * DMODEL + d] = cls[d];
}

// x[b, 1+p, :] = ptmp[b*196+p, :] + pos_emb[p, :]
__global__ __launch_bounds__(256) void add_pos_k(
    const float* __restrict__ ptmp, const float* __restrict__ pos,
    float* __restrict__ x)
{
    long long idx = (long long)blockIdx.x * 256 + threadIdx.x;
    int r = idx / DMODEL, d = idx - (long long)r * DMODEL;
    int b = r / NPATCH, p = r - b * NPATCH;
    x[((long long)b * S_LEN + 1 + p) * DMODEL + d] = ptmp[idx] + pos[(long long)p * DMODEL + d];
}

// =====================================================================
// tiled transpose + convert (patch_W only): src [R][C] fp32 -> dst [C][R] bf16
// =====================================================================
__global__ __launch_bounds__(256) void transpose_conv_k(
    const float* __restrict__ src, bf16* __restrict__ dst, int R, int C)
{
    __shared__ float t[32][33];
    int tx = threadIdx.x & 31, ty = threadIdx.x >> 5;
    int c0 = blockIdx.x * 32, r0 = blockIdx.y * 32;
#pragma unroll
    for (int i = 0; i < 4; ++i) {
        int r = r0 + ty + i * 8;
        if (r < R && c0 + tx < C) t[ty + i * 8][tx] = src[(long long)r * C + c0 + tx];
    }
    __syncthreads();
#pragma unroll
    for (int i = 0; i < 4; ++i) {
        int c = c0 + ty + i * 8;
        if (c < C && r0 + tx < R) dst[(long long)c * R + r0 + tx] = __float2bfloat16(t[tx][ty + i * 8]);
    }
}

// =====================================================================
// per-layer weight conversion: Wq/Wk/Wv (per head), Wo, W1, W2 -> bf16 [N][K]
// + qkv bias pack. One launch, grid = 6913 tile-jobs of 32x32.
// =====================================================================
__global__ __launch_bounds__(256) void conv_layer_k(
    const float* __restrict__ Wq, const float* __restrict__ Wk, const float* __restrict__ Wv,
    const float* __restrict__ Wo, const float* __restrict__ W1, const float* __restrict__ W2,
    const float* __restrict__ bq, const float* __restrict__ bk, const float* __restrict__ bv,
    bf16* __restrict__ wqkv_t, bf16* __restrict__ wo_t,
    bf16* __restrict__ w1_t, bf16* __restrict__ w2_t, float* __restrict__ bqkv)
{
    int t = blockIdx.x;
    int tid = threadIdx.x;
    if (t == 6912) {
        for (int i = tid; i < 2304; i += 256) {
            int m = i / 768, r = i - m * 768;
            bqkv[i] = (m == 0 ? bq : m == 1 ? bk : bv)[r];
        }
        return;
    }
    const float* src; bf16* dst;
    int C; long long dld;
    int r0, c0;
    if (t < 1728) {                       // qkv heads: slab = mat*12+h, 768x64 each
        int slab = t / 48, rem = t - slab * 48;
        int mat = slab / 12, h = slab - mat * 12;
        src = (mat == 0 ? Wq : mat == 1 ? Wk : Wv) + (long long)h * 768 * 64;
        dst = wqkv_t + ((long long)mat * 768 + h * 64) * 768;
        C = 64; dld = 768;
        r0 = (rem >> 1) * 32; c0 = (rem & 1) * 32;
    } else if (t < 2304) {                // Wo 768x768
        int rem = t - 1728;
        src = Wo; dst = wo_t; C = 768; dld = 768;
        r0 = (rem / 24) * 32; c0 = (rem % 24) * 32;
    } else if (t < 4608) {                // W1 768x3072
        int rem = t - 2304;
        src = W1; dst = w1_t; C = 3072; dld = 768;
        r0 = (rem / 96) * 32; c0 = (rem % 96) * 32;
    } else {                              // W2 3072x768
        int rem = t - 4608;
        src = W2; dst = w2_t; C = 768; dld = 3072;
        r0 = (rem / 24) * 32; c0 = (rem % 24) * 32;
    }
    __shared__ float tile[32][33];
    int tx = tid & 31, ty = tid >> 5;
#pragma unroll
    for (int i = 0; i < 4; ++i)
        tile[ty + i * 8][tx] = src[(long long)(r0 + ty + i * 8) * C + c0 + tx];
    __syncthreads();
#pragma unroll
    for (int i = 0; i < 4; ++i)
        dst[(long long)(c0 + ty + i * 8) * dld + r0 + tx] = __float2bfloat16(tile[tx][ty + i * 8]);
}

// =====================================================================
// V transpose: qkv bf16 [6304][2304] (V at col 1536+h*64+e) ->
// Vt [384][64][224] bf16, zero pad s>=197
// grid (7, 2, 384), block 256
// =====================================================================
__global__ __launch_bounds__(256) void vt_k(
    const bf16* __restrict__ qkv, bf16* __restrict__ Vt)
{
    int z = blockIdx.z;
    int b = z / NHEAD, h = z - b * NHEAD;
    int s0 = blockIdx.x * 32, e0 = blockIdx.y * 32;
    __shared__ bf16 t[32][33];
    int tx = threadIdx.x & 31, ty = threadIdx.x >> 5;
#pragma unroll
    for (int i = 0; i < 4; ++i) {
        int s = s0 + ty + i * 8;
        bf16 v = __float2bfloat16(0.f);
        if (s < S_LEN) v = qkv[((long long)(b * S_LEN + s)) * 2304 + 1536 + h * 64 + e0 + tx];
        t[ty + i * 8][tx] = v;
    }
    __syncthreads();
#pragma unroll
    for (int i = 0; i < 4; ++i) {
        int e = e0 + ty + i * 8;
        Vt[((long long)z * 64 + e) * 224 + s0 + tx] = t[tx][ty + i * 8];
    }
}

// =====================================================================
// LayerNorm over last dim (768)
// =====================================================================
__global__ __launch_bounds__(256) void ln_k(
    const float* __restrict__ xin, long long instride,
    const float* __restrict__ g, const float* __restrict__ b,
    float* __restrict__ xout, long long outstride)
{
    int row = blockIdx.x;
    const float* xr = xin + (long long)row * instride;
    float* orow = xout + (long long)row * outstride;
    int tid = threadIdx.x;
    float v0 = xr[tid], v1 = xr[tid + 256], v2 = xr[tid + 512];
    __shared__ float s[256];
    s[tid] = v0 + v1 + v2;
    __syncthreads();
    for (int st = 128; st > 0; st >>= 1) { if (tid < st) s[tid] += s[tid + st]; __syncthreads(); }
    float mean = s[0] * (1.0f / DMODEL);
    __syncthreads();
    float d0 = v0 - mean, d1 = v1 - mean, d2 = v2 - mean;
    s[tid] = d0 * d0 + d1 * d1 + d2 * d2;
    __syncthreads();
    for (int st = 128; st > 0; st >>= 1) { if (tid < st) s[tid] += s[tid + st]; __syncthreads(); }
    float rs = rsqrtf(s[0] * (1.0f / DMODEL) + 1e-5f);
    orow[tid]       = d0 * rs * g[tid]       + b[tid];
    orow[tid + 256] = d1 * rs * g[tid + 256] + b[tid + 256];
    orow[tid + 512] = d2 * rs * g[tid + 512] + b[tid + 512];
}

__global__ __launch_bounds__(256) void ln_bf_k(
    const float* __restrict__ xin, long long instride,
    const float* __restrict__ g, const float* __restrict__ b,
    bf16* __restrict__ xout, long long outstride)
{
    int row = blockIdx.x;
    const float* xr = xin + (long long)row * instride;
    bf16* orow = xout + (long long)row * outstride;
    int tid = threadIdx.x;
    float v0 = xr[tid], v1 = xr[tid + 256], v2 = xr[tid + 512];
    __shared__ float s[256];
    s[tid] = v0 + v1 + v2;
    __syncthreads();
    for (int st = 128; st > 0; st >>= 1) { if (tid < st) s[tid] += s[tid + st]; __syncthreads(); }
    float mean = s[0] * (1.0f / DMODEL);
    __syncthreads();
    float d0 = v0 - mean, d1 = v1 - mean, d2 = v2 - mean;
    s[tid] = d0 * d0 + d1 * d1 + d2 * d2;
    __syncthreads();
    for (int st = 128; st > 0; st >>= 1) { if (tid < st) s[tid] += s[tid + st]; __syncthreads(); }
    float rs = rsqrtf(s[0] * (1.0f / DMODEL) + 1e-5f);
    orow[tid]       = __float2bfloat16(d0 * rs * g[tid]       + b[tid]);
    orow[tid + 256] = __float2bfloat16(d1 * rs * g[tid + 256] + b[tid + 256]);
    orow[tid + 512] = __float2bfloat16(d2 * rs * g[tid + 512] + b[tid + 512]);
}

// =====================================================================
// MFMA fused attention. grid (4 qtiles, 384 z), 256 thr (4 waves).
// Wave w handles q rows [qb*64 + w*16, +16).
// LDS: KP = K B-fragments (26 frags, reused as P A-fragments 28 frags)
//      Vs = V B-fragments (28 frags)
// =====================================================================
__global__ __launch_bounds__(256) void attn_k(
    const bf16* __restrict__ qkvb, const bf16* __restrict__ Vtb,
    bf16* __restrict__ Ob)
{
    __shared__ short KP[14336];   // 28 KB
    __shared__ short Vs[14336];   // 28 KB

    int tid = threadIdx.x;
    int lane = tid & 63, wid = tid >> 6;
    int rl = lane & 15, quad = lane >> 4;
    int qb = blockIdx.x;
    int z = blockIdx.y;
    int b = z / NHEAD, h = z - b * NHEAD;
    const short* qg = (const short*)qkvb;
    const short* vg = (const short*)Vtb;

    // ---- stage K (26 frags) and V (28 frags) via global_load_lds ----
#pragma unroll
    for (int c = 0; c < 7; ++c) {
        int f = wid * 7 + c;
        if (f < 26) {
            int jn = f >> 1, s = f & 1;
            int krow = jn * 16 + rl; if (krow > 196) krow = 196;
            const short* src = qg + ((long long)(b * S_LEN + krow) * 2304 + 768 + h * 64 + s * 32 + quad * 8);
            __builtin_amdgcn_global_load_lds((GLOBAL_AS const void*)src,
                                             (LDS_AS void*)&KP[f * 512], 16, 0, 0);
        }
        {
            int et = f / 7, s2 = f - et * 7;
            int e = et * 16 + rl;
            const short* src = vg + ((long long)(z * 64 + e) * 224 + s2 * 32 + quad * 8);
            __builtin_amdgcn_global_load_lds((GLOBAL_AS const void*)src,
                                             (LDS_AS void*)&Vs[f * 512], 16, 0, 0);
        }
    }
    // ---- Q A-fragments (direct global 16B loads) ----
    int qrow = qb * 64 + wid * 16 + rl;
    int qrc = qrow > 196 ? 196 : qrow;
    long long qbase = (long long)(b * S_LEN + qrc) * 2304 + h * 64 + quad * 8;
    short8 q0 = *(const short8*)(qg + qbase);
    short8 q1 = *(const short8*)(qg + qbase + 32);
    __syncthreads();

    // ---- S = Q K^T ----
    f32x4 accS[13];
#pragma unroll
    for (int jn = 0; jn < 13; ++jn) accS[jn] = (f32x4){0.f, 0.f, 0.f, 0.f};
#pragma unroll
    for (int jn = 0; jn < 13; ++jn) {
        short8 b0 = *(const short8*)&KP[(jn * 2 + 0) * 512 + lane * 8];
        short8 b1 = *(const short8*)&KP[(jn * 2 + 1) * 512 + lane * 8];
        accS[jn] = __builtin_amdgcn_mfma_f32_16x16x32_bf16(q0, b0, accS[jn], 0, 0, 0);
        accS[jn] = __builtin_amdgcn_mfma_f32_16x16x32_bf16(q1, b1, accS[jn], 0, 0, 0);
    }
    __syncthreads();   // all K reads complete before P overwrites KP

    // ---- in-register softmax (rows = quad*4+r, col = jn*16+rl) ----
    float mx[4] = {-1e30f, -1e30f, -1e30f, -1e30f};
    float sm[4] = {0.f, 0.f, 0.f, 0.f};
#pragma unroll
    for (int r = 0; r < 4; ++r) {
#pragma unroll
        for (int jn = 0; jn < 13; ++jn) {
            int col = jn * 16 + rl;
            if (col < S_LEN) mx[r] = fmaxf(mx[r], accS[jn][r] * 0.125f);
        }
#pragma unroll
        for (int d = 1; d < 16; d <<= 1) mx[r] = fmaxf(mx[r], __shfl_xor(mx[r], d, 64));
    }
    float pv[13][4];
#pragma unroll
    for (int jn = 0; jn < 13; ++jn) {
        int col = jn * 16 + rl;
#pragma unroll
        for (int r = 0; r < 4; ++r) {
            float p = (col < S_LEN) ? __expf(accS[jn][r] * 0.125f - mx[r]) : 0.f;
            pv[jn][r] = p;
            sm[r] += p;
        }
    }
#pragma unroll
    for (int r = 0; r < 4; ++r) {
#pragma unroll
        for (int d = 1; d < 16; d <<= 1) sm[r] += __shfl_xor(sm[r], d, 64);
        sm[r] = 1.0f / sm[r];
    }

    // ---- write P strip into KP as A-fragments (own-wave region) ----
    int pbase = wid * 7 * 512;
#pragma unroll
    for (int jn = 0; jn < 13; ++jn) {
        int col = jn * 16 + rl;
        int s2 = col >> 5, kk = col & 31;
        int lidx = (kk >> 3) * 16, j = kk & 7;
#pragma unroll
        for (int r = 0; r < 4; ++r) {
            int m = quad * 4 + r;
            KP[pbase + s2 * 512 + (m + lidx) * 8 + j] = bf16bits(pv[jn][r] * sm[r]);
        }
    }
    {   // zero pad cols 208..223 (kstep 6 upper half)
        int col = 208 + rl;
        int kk = col & 31;
        int lidx = (kk >> 3) * 16, j = kk & 7;
#pragma unroll
        for (int r = 0; r < 4; ++r) {
            int m = quad * 4 + r;
            KP[pbase + 6 * 512 + (m + lidx) * 8 + j] = 0;
        }
    }
    // own-wave write->read: compiler-inserted lgkmcnt handles ordering

    // ---- O = P V ----
    short8 pa[7];
#pragma unroll
    for (int s2 = 0; s2 < 7; ++s2) pa[s2] = *(const short8*)&KP[pbase + s2 * 512 + lane * 8];
    f32x4 accO[4];
#pragma unroll
    for (int et = 0; et < 4; ++et) accO[et] = (f32x4){0.f, 0.f, 0.f, 0.f};
#pragma unroll
    for (int et = 0; et < 4; ++et)
#pragma unroll
        for (int s2 = 0; s2 < 7; ++s2) {
            short8 bb = *(const short8*)&Vs[(et * 7 + s2) * 512 + lane * 8];
            accO[et] = __builtin_amdgcn_mfma_f32_16x16x32_bf16(pa[s2], bb, accO[et], 0, 0, 0);
        }

    // ---- epilogue: Ob[b, q, h*64+e] ----
#pragma unroll
    for (int et = 0; et < 4; ++et) {
        int e = et * 16 + rl;
#pragma unroll
        for (int r = 0; r < 4; ++r) {
            int q = qb * 64 + wid * 16 + quad * 4 + r;
            if (q < S_LEN)
                Ob[((long long)(b * S_LEN + q)) * DMODEL + h * 64 + e] = __float2bfloat16(accO[et][r]);
        }
    }
}

// =====================================================================
// fp32 GEMM (head only)
// =====================================================================
#define BM 64
#define BN 64
#define BK 16

__global__ __launch_bounds__(256) void gemm_k(
    const float* __restrict__ A, const float* __restrict__ B,
    const float* __restrict__ bias, float* __restrict__ C,
    int M, int N, int K, int lda, int ldb, int ldc)
{
    __shared__ float As[BK][BM + 1];
    __shared__ float Bs[BK][BN];
    int tid = threadIdx.x;
    int tx = tid & 15, ty = tid >> 4;
    int block_m = blockIdx.y * BM, block_n = blockIdx.x * BN;
    float acc[4][4] = {};
    int nk = (K + BK - 1) / BK;
    for (int kt = 0; kt < nk; ++kt) {
        int k0 = kt * BK;
        {
            int kk = tid & 15, mm = tid >> 4;
#pragma unroll
            for (int i = 0; i < 4; ++i) {
                int m = block_m + mm + i * 16, k = k0 + kk;
                float v = 0.f;
                if (m < M && k < K) v = A[(long long)m * lda + k];
                As[kk][mm + i * 16] = v;
            }
        }
        {
            int nn = tid & 63, kk4 = tid >> 6;
#pragma unroll
            for (int i = 0; i < 4; ++i) {
                int k = k0 + kk4 + i * 4, n = block_n + nn;
                float v = 0.f;
                if (k < K && n < N) v = B[(long long)k * ldb + n];
                Bs[kk4 + i * 4][nn] = v;
            }
        }
        __syncthreads();
#pragma unroll
        for (int kk = 0; kk < BK; ++kk) {
            float a[4], bb[4];
#pragma unroll
            for (int i = 0; i < 4; ++i) a[i] = As[kk][ty * 4 + i];
#pragma unroll
            for (int j = 0; j < 4; ++j) bb[j] = Bs[kk][tx * 4 + j];
#pragma unroll
            for (int i = 0; i < 4; ++i)
#pragma unroll
                for (int j = 0; j < 4; ++j)
                    acc[i][j] = fmaf(a[i], bb[j], acc[i][j]);
        }
        __syncthreads();
    }
#pragma unroll
    for (int i = 0; i < 4; ++i) {
        int m = block_m + ty * 4 + i;
        if (m >= M) continue;
#pragma unroll
        for (int j = 0; j < 4; ++j) {
            int n = block_n + tx * 4 + j;
            if (n >= N) continue;
            C[(long long)m * ldc + n] = acc[i][j] + bias[n];
        }
    }
}

// =====================================================================
// bf16 MFMA GEMM (m97 structure)
// =====================================================================
__global__ __launch_bounds__(256) void mfma_gemm_k(
    const bf16* __restrict__ A, const bf16* __restrict__ Bt,
    const float* __restrict__ bias, const float* __restrict__ resid,
    float* __restrict__ Cf, bf16* __restrict__ Cb,
    int M, int N, int K, int ldc, int ldr, int flags)
{
    __shared__ short As[4096];
    __shared__ short Bs[4096];

    int tid = threadIdx.x;
    int lane = tid & 63, wid = tid >> 6;
    int wm = wid & 1, wn = wid >> 1;
    long long block_m = (long long)blockIdx.y * 128;
    long long block_n = (long long)blockIdx.x * 128;

    const short* Ag = (const short*)A;
    const short* Bg = (const short*)Bt;

    int rl   = lane & 15;
    int koff = (lane >> 4) * 8;

    f32x4 acc[4][4] = {};

    for (int k0 = 0; k0 < K; k0 += 32) {
#pragma unroll
        for (int c = 0; c < 4; ++c) {
            int bi = wid * 4 + c;
            int rloc = (bi & 7) * 16 + rl;
            const short* src;
            short* dst;
            if (bi < 8) {
                long long grow = block_m + rloc;
                if (grow >= M) grow = M - 1;
                src = Ag + grow * K + k0 + koff;
                dst = &As[bi * 512];
            } else {
                long long grow = block_n + rloc;
                src = Bg + grow * K + k0 + koff;
                dst = &Bs[(bi - 8) * 512];
            }
            __builtin_amdgcn_global_load_lds((GLOBAL_AS const void*)src,
                                             (LDS_AS void*)dst, 16, 0, 0);
        }
        __syncthreads();

        short8 a[4], b[4];
        const short8* ap = (const short8*)As;
        const short8* bp = (const short8*)Bs;
#pragma unroll
        for (int i = 0; i < 4; ++i) a[i] = ap[(wm * 4 + i) * 64 + lane];
#pragma unroll
        for (int j = 0; j < 4; ++j) b[j] = bp[(wn * 4 + j) * 64 + lane];
#pragma unroll
        for (int i = 0; i < 4; ++i)
#pragma unroll
            for (int j = 0; j < 4; ++j)
                acc[i][j] = __builtin_amdgcn_mfma_f32_16x16x32_bf16(a[i], b[j], acc[i][j], 0, 0, 0);
        __syncthreads();
    }

    int cl = lane & 15;
    int rq = (lane >> 4) * 4;
#pragma unroll
    for (int j = 0; j < 4; ++j) {
        long long col = block_n + wn * 64 + j * 16 + cl;
        float bv = (flags & FLAG_BIAS) ? bias[col] : 0.f;
#pragma unroll
        for (int i = 0; i < 4; ++i) {
#pragma unroll
            for (int r = 0; r < 4; ++r) {
                long long row = block_m + wm * 64 + i * 16 + rq + r;
                if (row >= M) continue;
                float v = acc[i][j][r] + bv;
                if (flags & FLAG_GELU) v = 0.5f * v * (1.0f + erff(v * 0.70710678118f));
                if (flags & FLAG_RESID) v += resid[row * (long long)ldr + col];
                if (flags & FLAG_OUTBF16) Cb[row * (long long)ldc + col] = __float2bfloat16(v);
                else Cf[row * (long long)ldc + col] = v;
            }
        }
    }
}

static inline void launch_mfma(hipStream_t stream,
    const bf16* A, const bf16* Bt, const float* bias, const float* resid,
    float* Cf, bf16* Cb, int M, int N, int K, int ldc, int ldr, int flags)
{
    dim3 grid(N / 128, (M + 127) / 128);
    mfma_gemm_k<<<grid, dim3(256), 0, stream>>>(A, Bt, bias, resid, Cf, Cb, M, N, K, ldc, ldr, flags);
}

extern "C" void kernel_launch(void* const* d_in, const int* in_sizes, int n_in,
                              void* d_out, int out_size, void* d_ws, size_t ws_size,
                              hipStream_t stream)
{
    const float* images   = (const float*)d_in[0];
    const float* patch_W  = (const float*)d_in[1];
    const float* patch_b  = (const float*)d_in[2];
    const float* pos_emb  = (const float*)d_in[3];
    const float* cls      = (const float*)d_in[4];
    const float* ln1_g    = (const float*)d_in[5];
    const float* ln1_b    = (const float*)d_in[6];
    const float* Wq       = (const float*)d_in[7];
    const float* bq       = (const float*)d_in[8];
    const float* Wk       = (const float*)d_in[9];
    const float* bk       = (const float*)d_in[10];
    const float* Wv       = (const float*)d_in[11];
    const float* bv       = (const float*)d_in[12];
    const float* Wo       = (const float*)d_in[13];
    const float* bo       = (const float*)d_in[14];
    const float* ln2_g    = (const float*)d_in[15];
    const float* ln2_b    = (const float*)d_in[16];
    const float* W1       = (const float*)d_in[17];
    const float* b1       = (const float*)d_in[18];
    const float* W2       = (const float*)d_in[19];
    const float* b2       = (const float*)d_in[20];
    const float* head_g   = (const float*)d_in[21];
    const float* head_bn  = (const float*)d_in[22];
    const float* head_W   = (const float*)d_in[23];
    const float* head_bias= (const float*)d_in[24];
    float* out = (float*)d_out;

    // ---- workspace carve-up ----
    char* p = (char*)d_ws;
    auto alloc = [&](long long nbytes) { char* r = p; p += (nbytes + 255) & ~255LL; return r; };
    const long long SZ = (long long)NTOK * DMODEL;

    float* x      = (float*)alloc(SZ * 4);                          // residual fp32
    bf16*  xn     = (bf16*) alloc(SZ * 2);                          // LN out bf16
    bf16*  qkvb   = (bf16*) alloc((long long)NTOK * 2304 * 2);      // qkv bf16 (union ptmp fp32)
    float* ptmp   = (float*)qkvb;                                   // [6272,768] fp32 (19.3MB < 29MB)
    bf16*  Vt     = (bf16*) alloc((long long)384 * 64 * 224 * 2);   // V transposed, padded
    bf16*  h1     = (bf16*) alloc((long long)NTOK * FFDIM * 2);     // FFN mid
    bf16*  Ob     = (bf16*) alloc(SZ * 2);                          // attn out (union patches)
    bf16*  patches= Ob;
    bf16*  wqkv_t = (bf16*) alloc((long long)2304 * 768 * 2);
    bf16*  wo_t   = (bf16*) alloc((long long)768 * 768 * 2);
    bf16*  w1_t   = (bf16*) alloc((long long)3072 * 768 * 2);
    bf16*  w2_t   = (bf16*) alloc((long long)768 * 3072 * 2);
    bf16*  pw_t   = (bf16*) alloc((long long)768 * 768 * 2);
    float* bqkv   = (float*)alloc(2304 * 4);
    float* xcls   = (float*)alloc((long long)BATCHSZ * DMODEL * 4);

    // ---- embed ----
    extract_patches_k<<<dim3(BATCHSZ * NPATCH), dim3(256), 0, stream>>>(images, patches);
    transpose_conv_k<<<dim3(24, 24), dim3(256), 0, stream>>>(patch_W, pw_t, 768, 768);
    launch_mfma(stream, patches, pw_t, patch_b, nullptr, ptmp, nullptr,
                BATCHSZ * NPATCH, DMODEL, 768, DMODEL, 0, FLAG_BIAS);
    cls_fill_k<<<dim3(BATCHSZ * DMODEL / 256), dim3(256), 0, stream>>>(cls, x);
    add_pos_k<<<dim3((BATCHSZ * NPATCH * DMODEL) / 256), dim3(256), 0, stream>>>(ptmp, pos_emb, x);

    const long long WQKV_L = (long long)NHEAD * DMODEL * HDIM;
    for (int l = 0; l < NLAYER; ++l) {
        // one-launch weight conversion for this layer
        conv_layer_k<<<dim3(6913), dim3(256), 0, stream>>>(
            Wq + (long long)l * WQKV_L, Wk + (long long)l * WQKV_L, Wv + (long long)l * WQKV_L,
            Wo + (long long)l * DMODEL * DMODEL,
            W1 + (long long)l * DMODEL * FFDIM,
            W2 + (long long)l * FFDIM * DMODEL,
            bq + (long long)l * 768, bk + (long long)l * 768, bv + (long long)l * 768,
            wqkv_t, wo_t, w1_t, w2_t, bqkv);

        // ln1 -> bf16
        ln_bf_k<<<dim3(NTOK), dim3(256), 0, stream>>>(
            x, DMODEL, ln1_g + l * DMODEL, ln1_b + l * DMODEL, xn, DMODEL);

        // fused QKV -> bf16 [6304][2304]
        launch_mfma(stream, xn, wqkv_t, bqkv, nullptr, nullptr, qkvb,
                    NTOK, 2304, DMODEL, 2304, 0, FLAG_BIAS | FLAG_OUTBF16);

        // V transpose (padded, zero-filled)
        vt_k<<<dim3(7, 2, 384), dim3(256), 0, stream>>>(qkvb, Vt);

        // fused MFMA attention -> Ob bf16 [b,q,h*64+e]
        attn_k<<<dim3(4, 384), dim3(256), 0, stream>>>(qkvb, Vt, Ob);

        // x += Ob @ Wo + bo
        launch_mfma(stream, Ob, wo_t, bo + (long long)l * DMODEL, x, x, nullptr,
                    NTOK, DMODEL, DMODEL, DMODEL, DMODEL, FLAG_BIAS | FLAG_RESID);

        // ln2 -> bf16
        ln_bf_k<<<dim3(NTOK), dim3(256), 0, stream>>>(
            x, DMODEL, ln2_g + l * DMODEL, ln2_b + l * DMODEL, xn, DMODEL);

        // h1 = gelu(xn @ W1 + b1)
        launch_mfma(stream, xn, w1_t, b1 + (long long)l * FFDIM, nullptr, nullptr, h1,
                    NTOK, FFDIM, DMODEL, FFDIM, 0, FLAG_BIAS | FLAG_GELU | FLAG_OUTBF16);

        // x += h1 @ W2 + b2
        launch_mfma(stream, h1, w2_t, b2 + (long long)l * DMODEL, x, x, nullptr,
                    NTOK, DMODEL, FFDIM, DMODEL, DMODEL, FLAG_BIAS | FLAG_RESID);
    }

    // ---- head ----
    ln_k<<<dim3(BATCHSZ), dim3(256), 0, stream>>>(
        x, (long long)S_LEN * DMODEL, head_g, head_bn, xcls, DMODEL);
    gemm_k<<<dim3((NCLS + 63) / 64, 1), dim3(256), 0, stream>>>(
        xcls, head_W, head_bias, out, BATCHSZ, NCLS, DMODEL, DMODEL, NCLS, NCLS);
}

// Round 4
// 5005.785 us; speedup vs baseline: 5.5516x; 1.1065x over previous
//
#include <hip/hip_runtime.h>
#include <hip/hip_bf16.h>
#include <math.h>

// ---- problem constants ----
#define S_LEN   197
#define NPATCH  196
#define BATCHSZ 32
#define DMODEL  768
#define NHEAD   12
#define HDIM    64
#define FFDIM   3072
#define NLAYER  12
#define NCLS    1000
#define NTOK    (BATCHSZ * S_LEN)   // 6304

#define FLAG_BIAS    1
#define FLAG_RESID   2
#define FLAG_GELU    4
#define FLAG_OUTBF16 8

typedef __attribute__((ext_vector_type(8))) short short8;
typedef __attribute__((ext_vector_type(4))) float f32x4;
typedef __hip_bfloat16 bf16;

#define GLOBAL_AS __attribute__((address_space(1)))
#define LDS_AS    __attribute__((address_space(3)))

static __device__ __forceinline__ short bf16bits(float x) {
    bf16 b = __float2bfloat16(x);
    return *reinterpret_cast<short*>(&b);
}

// =====================================================================
// patch extraction -> bf16 patches [32*196, 768]
// =====================================================================
__global__ __launch_bounds__(256) void extract_patches_k(
    const float* __restrict__ images, bf16* __restrict__ patches)
{
    int r = blockIdx.x;              // b*196 + p
    int b = r / NPATCH, p = r - b * NPATCH;
    int i = p / 14, j = p - i * 14;
    int tid = threadIdx.x;
#pragma unroll
    for (int t = 0; t < 3; ++t) {
        int k = tid + t * 256;       // 0..767
        int pi = k / 48;
        int rem = k - pi * 48;
        int pj = rem / 3;
        int c  = rem - pj * 3;
        long long src = (((long long)(b * 224 + i * 16 + pi)) * 224 + (j * 16 + pj)) * 3 + c;
        patches[(long long)r * 768 + k] = __float2bfloat16(images[src]);
    }
}

// x[b,s,:] = s==0 ? cls : ptmp[b*196+s-1,:] + pos[s-1,:]
__global__ __launch_bounds__(256) void embed_k(
    const float* __restrict__ ptmp, const float* __restrict__ pos,
    const float* __restrict__ cls, float* __restrict__ x)
{
    long long idx = (long long)blockIdx.x * 256 + threadIdx.x;  // 32*197*768
    int d = idx % DMODEL;
    long long r = idx / DMODEL;
    int b = r / S_LEN, s = r - (long long)b * S_LEN;
    float v;
    if (s == 0) v = cls[d];
    else v = ptmp[((long long)b * NPATCH + s - 1) * DMODEL + d] + pos[(long long)(s - 1) * DMODEL + d];
    x[idx] = v;
}

// =====================================================================
// tiled transpose + convert (patch_W only)
// =====================================================================
__global__ __launch_bounds__(256) void transpose_conv_k(
    const float* __restrict__ src, bf16* __restrict__ dst, int R, int C)
{
    __shared__ float t[32][33];
    int tx = threadIdx.x & 31, ty = threadIdx.x >> 5;
    int c0 = blockIdx.x * 32, r0 = blockIdx.y * 32;
#pragma unroll
    for (int i = 0; i < 4; ++i) {
        int r = r0 + ty + i * 8;
        if (r < R && c0 + tx < C) t[ty + i * 8][tx] = src[(long long)r * C + c0 + tx];
    }
    __syncthreads();
#pragma unroll
    for (int i = 0; i < 4; ++i) {
        int c = c0 + ty + i * 8;
        if (c < C && r0 + tx < R) dst[(long long)c * R + r0 + tx] = __float2bfloat16(t[tx][ty + i * 8]);
    }
}

// =====================================================================
// per-layer weight conversion -> bf16 [N][K] + qkv bias pack
// =====================================================================
__global__ __launch_bounds__(256) void conv_layer_k(
    const float* __restrict__ Wq, const float* __restrict__ Wk, const float* __restrict__ Wv,
    const float* __restrict__ Wo, const float* __restrict__ W1, const float* __restrict__ W2,
    const float* __restrict__ bq, const float* __restrict__ bk, const float* __restrict__ bv,
    bf16* __restrict__ wqkv_t, bf16* __restrict__ wo_t,
    bf16* __restrict__ w1_t, bf16* __restrict__ w2_t, float* __restrict__ bqkv)
{
    int t = blockIdx.x;
    int tid = threadIdx.x;
    if (t == 6912) {
        for (int i = tid; i < 2304; i += 256) {
            int m = i / 768, r = i - m * 768;
            bqkv[i] = (m == 0 ? bq : m == 1 ? bk : bv)[r];
        }
        return;
    }
    const float* src; bf16* dst;
    int C; long long dld;
    int r0, c0;
    if (t < 1728) {
        int slab = t / 48, rem = t - slab * 48;
        int mat = slab / 12, h = slab - mat * 12;
        src = (mat == 0 ? Wq : mat == 1 ? Wk : Wv) + (long long)h * 768 * 64;
        dst = wqkv_t + ((long long)mat * 768 + h * 64) * 768;
        C = 64; dld = 768;
        r0 = (rem >> 1) * 32; c0 = (rem & 1) * 32;
    } else if (t < 2304) {
        int rem = t - 1728;
        src = Wo; dst = wo_t; C = 768; dld = 768;
        r0 = (rem / 24) * 32; c0 = (rem % 24) * 32;
    } else if (t < 4608) {
        int rem = t - 2304;
        src = W1; dst = w1_t; C = 3072; dld = 768;
        r0 = (rem / 96) * 32; c0 = (rem % 96) * 32;
    } else {
        int rem = t - 4608;
        src = W2; dst = w2_t; C = 768; dld = 3072;
        r0 = (rem / 24) * 32; c0 = (rem % 24) * 32;
    }
    __shared__ float tile[32][33];
    int tx = tid & 31, ty = tid >> 5;
#pragma unroll
    for (int i = 0; i < 4; ++i)
        tile[ty + i * 8][tx] = src[(long long)(r0 + ty + i * 8) * C + c0 + tx];
    __syncthreads();
#pragma unroll
    for (int i = 0; i < 4; ++i)
        dst[(long long)(c0 + ty + i * 8) * dld + r0 + tx] = __float2bfloat16(tile[tx][ty + i * 8]);
}

// =====================================================================
// V transpose: qkv bf16 -> Vt [384][64][224], zero pad s>=197
// =====================================================================
__global__ __launch_bounds__(256) void vt_k(
    const bf16* __restrict__ qkv, bf16* __restrict__ Vt)
{
    int z = blockIdx.z;
    int b = z / NHEAD, h = z - b * NHEAD;
    int s0 = blockIdx.x * 32, e0 = blockIdx.y * 32;
    __shared__ bf16 t[32][33];
    int tx = threadIdx.x & 31, ty = threadIdx.x >> 5;
#pragma unroll
    for (int i = 0; i < 4; ++i) {
        int s = s0 + ty + i * 8;
        bf16 v = __float2bfloat16(0.f);
        if (s < S_LEN) v = qkv[((long long)(b * S_LEN + s)) * 2304 + 1536 + h * 64 + e0 + tx];
        t[ty + i * 8][tx] = v;
    }
    __syncthreads();
#pragma unroll
    for (int i = 0; i < 4; ++i) {
        int e = e0 + ty + i * 8;
        Vt[((long long)z * 64 + e) * 224 + s0 + tx] = t[tx][ty + i * 8];
    }
}

// =====================================================================
// LayerNorm over last dim (768)
// =====================================================================
__global__ __launch_bounds__(256) void ln_k(
    const float* __restrict__ xin, long long instride,
    const float* __restrict__ g, const float* __restrict__ b,
    float* __restrict__ xout, long long outstride)
{
    int row = blockIdx.x;
    const float* xr = xin + (long long)row * instride;
    float* orow = xout + (long long)row * outstride;
    int tid = threadIdx.x;
    float v0 = xr[tid], v1 = xr[tid + 256], v2 = xr[tid + 512];
    __shared__ float s[256];
    s[tid] = v0 + v1 + v2;
    __syncthreads();
    for (int st = 128; st > 0; st >>= 1) { if (tid < st) s[tid] += s[tid + st]; __syncthreads(); }
    float mean = s[0] * (1.0f / DMODEL);
    __syncthreads();
    float d0 = v0 - mean, d1 = v1 - mean, d2 = v2 - mean;
    s[tid] = d0 * d0 + d1 * d1 + d2 * d2;
    __syncthreads();
    for (int st = 128; st > 0; st >>= 1) { if (tid < st) s[tid] += s[tid + st]; __syncthreads(); }
    float rs = rsqrtf(s[0] * (1.0f / DMODEL) + 1e-5f);
    orow[tid]       = d0 * rs * g[tid]       + b[tid];
    orow[tid + 256] = d1 * rs * g[tid + 256] + b[tid + 256];
    orow[tid + 512] = d2 * rs * g[tid + 512] + b[tid + 512];
}

__global__ __launch_bounds__(256) void ln_bf_k(
    const float* __restrict__ xin, long long instride,
    const float* __restrict__ g, const float* __restrict__ b,
    bf16* __restrict__ xout, long long outstride)
{
    int row = blockIdx.x;
    const float* xr = xin + (long long)row * instride;
    bf16* orow = xout + (long long)row * outstride;
    int tid = threadIdx.x;
    float v0 = xr[tid], v1 = xr[tid + 256], v2 = xr[tid + 512];
    __shared__ float s[256];
    s[tid] = v0 + v1 + v2;
    __syncthreads();
    for (int st = 128; st > 0; st >>= 1) { if (tid < st) s[tid] += s[tid + st]; __syncthreads(); }
    float mean = s[0] * (1.0f / DMODEL);
    __syncthreads();
    float d0 = v0 - mean, d1 = v1 - mean, d2 = v2 - mean;
    s[tid] = d0 * d0 + d1 * d1 + d2 * d2;
    __syncthreads();
    for (int st = 128; st > 0; st >>= 1) { if (tid < st) s[tid] += s[tid + st]; __syncthreads(); }
    float rs = rsqrtf(s[0] * (1.0f / DMODEL) + 1e-5f);
    orow[tid]       = __float2bfloat16(d0 * rs * g[tid]       + b[tid]);
    orow[tid + 256] = __float2bfloat16(d1 * rs * g[tid + 256] + b[tid + 256]);
    orow[tid + 512] = __float2bfloat16(d2 * rs * g[tid + 512] + b[tid + 512]);
}

// =====================================================================
// MFMA fused attention (unchanged from R3 — verified correct)
// =====================================================================
__global__ __launch_bounds__(256) void attn_k(
    const bf16* __restrict__ qkvb, const bf16* __restrict__ Vtb,
    bf16* __restrict__ Ob)
{
    __shared__ short KP[14336];
    __shared__ short Vs[14336];

    int tid = threadIdx.x;
    int lane = tid & 63, wid = tid >> 6;
    int rl = lane & 15, quad = lane >> 4;
    int qb = blockIdx.x;
    int z = blockIdx.y;
    int b = z / NHEAD, h = z - b * NHEAD;
    const short* qg = (const short*)qkvb;
    const short* vg = (const short*)Vtb;

#pragma unroll
    for (int c = 0; c < 7; ++c) {
        int f = wid * 7 + c;
        if (f < 26) {
            int jn = f >> 1, s = f & 1;
            int krow = jn * 16 + rl; if (krow > 196) krow = 196;
            const short* src = qg + ((long long)(b * S_LEN + krow) * 2304 + 768 + h * 64 + s * 32 + quad * 8);
            __builtin_amdgcn_global_load_lds((GLOBAL_AS const void*)src,
                                             (LDS_AS void*)&KP[f * 512], 16, 0, 0);
        }
        {
            int et = f / 7, s2 = f - et * 7;
            int e = et * 16 + rl;
            const short* src = vg + ((long long)(z * 64 + e) * 224 + s2 * 32 + quad * 8);
            __builtin_amdgcn_global_load_lds((GLOBAL_AS const void*)src,
                                             (LDS_AS void*)&Vs[f * 512], 16, 0, 0);
        }
    }
    int qrow = qb * 64 + wid * 16 + rl;
    int qrc = qrow > 196 ? 196 : qrow;
    long long qbase = (long long)(b * S_LEN + qrc) * 2304 + h * 64 + quad * 8;
    short8 q0 = *(const short8*)(qg + qbase);
    short8 q1 = *(const short8*)(qg + qbase + 32);
    __syncthreads();

    f32x4 accS[13];
#pragma unroll
    for (int jn = 0; jn < 13; ++jn) accS[jn] = (f32x4){0.f, 0.f, 0.f, 0.f};
#pragma unroll
    for (int jn = 0; jn < 13; ++jn) {
        short8 b0 = *(const short8*)&KP[(jn * 2 + 0) * 512 + lane * 8];
        short8 b1 = *(const short8*)&KP[(jn * 2 + 1) * 512 + lane * 8];
        accS[jn] = __builtin_amdgcn_mfma_f32_16x16x32_bf16(q0, b0, accS[jn], 0, 0, 0);
        accS[jn] = __builtin_amdgcn_mfma_f32_16x16x32_bf16(q1, b1, accS[jn], 0, 0, 0);
    }
    __syncthreads();

    float mx[4] = {-1e30f, -1e30f, -1e30f, -1e30f};
    float sm[4] = {0.f, 0.f, 0.f, 0.f};
#pragma unroll
    for (int r = 0; r < 4; ++r) {
#pragma unroll
        for (int jn = 0; jn < 13; ++jn) {
            int col = jn * 16 + rl;
            if (col < S_LEN) mx[r] = fmaxf(mx[r], accS[jn][r] * 0.125f);
        }
#pragma unroll
        for (int d = 1; d < 16; d <<= 1) mx[r] = fmaxf(mx[r], __shfl_xor(mx[r], d, 64));
    }
    float pv[13][4];
#pragma unroll
    for (int jn = 0; jn < 13; ++jn) {
        int col = jn * 16 + rl;
#pragma unroll
        for (int r = 0; r < 4; ++r) {
            float p = (col < S_LEN) ? __expf(accS[jn][r] * 0.125f - mx[r]) : 0.f;
            pv[jn][r] = p;
            sm[r] += p;
        }
    }
#pragma unroll
    for (int r = 0; r < 4; ++r) {
#pragma unroll
        for (int d = 1; d < 16; d <<= 1) sm[r] += __shfl_xor(sm[r], d, 64);
        sm[r] = 1.0f / sm[r];
    }

    int pbase = wid * 7 * 512;
#pragma unroll
    for (int jn = 0; jn < 13; ++jn) {
        int col = jn * 16 + rl;
        int s2 = col >> 5, kk = col & 31;
        int lidx = (kk >> 3) * 16, j = kk & 7;
#pragma unroll
        for (int r = 0; r < 4; ++r) {
            int m = quad * 4 + r;
            KP[pbase + s2 * 512 + (m + lidx) * 8 + j] = bf16bits(pv[jn][r] * sm[r]);
        }
    }
    {
        int col = 208 + rl;
        int kk = col & 31;
        int lidx = (kk >> 3) * 16, j = kk & 7;
#pragma unroll
        for (int r = 0; r < 4; ++r) {
            int m = quad * 4 + r;
            KP[pbase + 6 * 512 + (m + lidx) * 8 + j] = 0;
        }
    }

    short8 pa[7];
#pragma unroll
    for (int s2 = 0; s2 < 7; ++s2) pa[s2] = *(const short8*)&KP[pbase + s2 * 512 + lane * 8];
    f32x4 accO[4];
#pragma unroll
    for (int et = 0; et < 4; ++et) accO[et] = (f32x4){0.f, 0.f, 0.f, 0.f};
#pragma unroll
    for (int et = 0; et < 4; ++et)
#pragma unroll
        for (int s2 = 0; s2 < 7; ++s2) {
            short8 bb = *(const short8*)&Vs[(et * 7 + s2) * 512 + lane * 8];
            accO[et] = __builtin_amdgcn_mfma_f32_16x16x32_bf16(pa[s2], bb, accO[et], 0, 0, 0);
        }

#pragma unroll
    for (int et = 0; et < 4; ++et) {
        int e = et * 16 + rl;
#pragma unroll
        for (int r = 0; r < 4; ++r) {
            int q = qb * 64 + wid * 16 + quad * 4 + r;
            if (q < S_LEN)
                Ob[((long long)(b * S_LEN + q)) * DMODEL + h * 64 + e] = __float2bfloat16(accO[et][r]);
        }
    }
}

// =====================================================================
// head: out[b][n] = dot(xcls[b], head_W[:,n]) + bias[n]
// grid (16 ntiles, 32 b), 256 thr: n = tid&63, kq = tid>>6 (192 k each)
// =====================================================================
__global__ __launch_bounds__(256) void head_k(
    const float* __restrict__ xcls, const float* __restrict__ W,
    const float* __restrict__ bias, float* __restrict__ out)
{
    int nt = blockIdx.x, b = blockIdx.y;
    int tid = threadIdx.x;
    int nl = tid & 63, kq = tid >> 6;
    int n = nt * 64 + nl;
    __shared__ float xs[DMODEL];
    for (int i = tid; i < DMODEL; i += 256) xs[i] = xcls[(long long)b * DMODEL + i];
    __syncthreads();
    float sum = 0.f;
    if (n < NCLS) {
        const float* Wp = W + (long long)kq * 192 * NCLS + n;
#pragma unroll 8
        for (int k = 0; k < 192; ++k)
            sum = fmaf(xs[kq * 192 + k], Wp[(long long)k * NCLS], sum);
    }
    __shared__ float red[256];
    red[tid] = sum;
    __syncthreads();
    if (kq == 0 && n < NCLS)
        out[(long long)b * NCLS + n] = red[nl] + red[nl + 64] + red[nl + 128] + red[nl + 192] + bias[n];
}

// x[i] += t0[i] + t1[i] + b2[col]   (float4 vectorized, 768 cols)
__global__ __launch_bounds__(256) void resid2_k(
    const float* __restrict__ t0, const float* __restrict__ t1,
    const float* __restrict__ b2, float* __restrict__ x)
{
    long long i = (long long)blockIdx.x * 256 + threadIdx.x;   // float4 index
    int col4 = i % (DMODEL / 4);
    const f32x4* t0v = (const f32x4*)t0;
    const f32x4* t1v = (const f32x4*)t1;
    const f32x4* b2v = (const f32x4*)b2;
    f32x4* xv = (f32x4*)x;
    f32x4 v = xv[i];
    f32x4 a = t0v[i], b = t1v[i], c = b2v[col4];
    v.x += a.x + b.x + c.x;
    v.y += a.y + b.y + c.y;
    v.z += a.z + b.z + c.z;
    v.w += a.w + b.w + c.w;
    xv[i] = v;
}

// =====================================================================
// bf16 MFMA GEMM (m97 structure) with optional K-split via blockIdx.z
// A [M][lda], Bt [N][ldb] both bf16; per-z offsets zA,zB (elements), zC.
// =====================================================================
__global__ __launch_bounds__(256) void mfma_gemm_k(
    const bf16* __restrict__ A, const bf16* __restrict__ Bt,
    const float* __restrict__ bias, const float* __restrict__ resid,
    float* __restrict__ Cf, bf16* __restrict__ Cb,
    int M, int N, int K, int lda, int ldb, int ldc, int ldr,
    long long zA, long long zB, long long zC, int flags)
{
    __shared__ short As[4096];
    __shared__ short Bs[4096];

    int tid = threadIdx.x;
    int lane = tid & 63, wid = tid >> 6;
    int wm = wid & 1, wn = wid >> 1;
    long long block_m = (long long)blockIdx.y * 128;
    long long block_n = (long long)blockIdx.x * 128;
    int zz = blockIdx.z;

    const short* Ag = (const short*)A + zz * zA;
    const short* Bg = (const short*)Bt + zz * zB;
    if (Cf) Cf += zz * zC;
    if (Cb) Cb += zz * zC;

    int rl   = lane & 15;
    int koff = (lane >> 4) * 8;

    f32x4 acc[4][4] = {};

    for (int k0 = 0; k0 < K; k0 += 32) {
#pragma unroll
        for (int c = 0; c < 4; ++c) {
            int bi = wid * 4 + c;
            int rloc = (bi & 7) * 16 + rl;
            const short* src;
            short* dst;
            if (bi < 8) {
                long long grow = block_m + rloc;
                if (grow >= M) grow = M - 1;
                src = Ag + grow * lda + k0 + koff;
                dst = &As[bi * 512];
            } else {
                long long grow = block_n + rloc;
                src = Bg + grow * ldb + k0 + koff;
                dst = &Bs[(bi - 8) * 512];
            }
            __builtin_amdgcn_global_load_lds((GLOBAL_AS const void*)src,
                                             (LDS_AS void*)dst, 16, 0, 0);
        }
        __syncthreads();

        short8 a[4], b[4];
        const short8* ap = (const short8*)As;
        const short8* bp = (const short8*)Bs;
#pragma unroll
        for (int i = 0; i < 4; ++i) a[i] = ap[(wm * 4 + i) * 64 + lane];
#pragma unroll
        for (int j = 0; j < 4; ++j) b[j] = bp[(wn * 4 + j) * 64 + lane];
#pragma unroll
        for (int i = 0; i < 4; ++i)
#pragma unroll
            for (int j = 0; j < 4; ++j)
                acc[i][j] = __builtin_amdgcn_mfma_f32_16x16x32_bf16(a[i], b[j], acc[i][j], 0, 0, 0);
        __syncthreads();
    }

    int cl = lane & 15;
    int rq = (lane >> 4) * 4;
#pragma unroll
    for (int j = 0; j < 4; ++j) {
        long long col = block_n + wn * 64 + j * 16 + cl;
        float bv = (flags & FLAG_BIAS) ? bias[col] : 0.f;
#pragma unroll
        for (int i = 0; i < 4; ++i) {
#pragma unroll
            for (int r = 0; r < 4; ++r) {
                long long row = block_m + wm * 64 + i * 16 + rq + r;
                if (row >= M) continue;
                float v = acc[i][j][r] + bv;
                if (flags & FLAG_GELU) v = 0.5f * v * (1.0f + erff(v * 0.70710678118f));
                if (flags & FLAG_RESID) v += resid[row * (long long)ldr + col];
                if (flags & FLAG_OUTBF16) Cb[row * (long long)ldc + col] = __float2bfloat16(v);
                else Cf[row * (long long)ldc + col] = v;
            }
        }
    }
}

static inline void launch_mfma(hipStream_t stream,
    const bf16* A, const bf16* Bt, const float* bias, const float* resid,
    float* Cf, bf16* Cb, int M, int N, int K, int ldc, int ldr, int flags)
{
    dim3 grid(N / 128, (M + 127) / 128, 1);
    mfma_gemm_k<<<grid, dim3(256), 0, stream>>>(A, Bt, bias, resid, Cf, Cb,
        M, N, K, K, K, ldc, ldr, 0, 0, 0, flags);
}

extern "C" void kernel_launch(void* const* d_in, const int* in_sizes, int n_in,
                              void* d_out, int out_size, void* d_ws, size_t ws_size,
                              hipStream_t stream)
{
    const float* images   = (const float*)d_in[0];
    const float* patch_W  = (const float*)d_in[1];
    const float* patch_b  = (const float*)d_in[2];
    const float* pos_emb  = (const float*)d_in[3];
    const float* cls      = (const float*)d_in[4];
    const float* ln1_g    = (const float*)d_in[5];
    const float* ln1_b    = (const float*)d_in[6];
    const float* Wq       = (const float*)d_in[7];
    const float* bq       = (const float*)d_in[8];
    const float* Wk       = (const float*)d_in[9];
    const float* bk       = (const float*)d_in[10];
    const float* Wv       = (const float*)d_in[11];
    const float* bv       = (const float*)d_in[12];
    const float* Wo       = (const float*)d_in[13];
    const float* bo       = (const float*)d_in[14];
    const float* ln2_g    = (const float*)d_in[15];
    const float* ln2_b    = (const float*)d_in[16];
    const float* W1       = (const float*)d_in[17];
    const float* b1       = (const float*)d_in[18];
    const float* W2       = (const float*)d_in[19];
    const float* b2       = (const float*)d_in[20];
    const float* head_g   = (const float*)d_in[21];
    const float* head_bn  = (const float*)d_in[22];
    const float* head_W   = (const float*)d_in[23];
    const float* head_bias= (const float*)d_in[24];
    float* out = (float*)d_out;

    // ---- workspace carve-up ----
    char* p = (char*)d_ws;
    auto alloc = [&](long long nbytes) { char* r = p; p += (nbytes + 255) & ~255LL; return r; };
    const long long SZ = (long long)NTOK * DMODEL;

    float* x      = (float*)alloc(SZ * 4);                          // residual fp32
    bf16*  xn     = (bf16*) alloc(SZ * 2);                          // LN out bf16
    bf16*  qkvb   = (bf16*) alloc((long long)NTOK * 2304 * 2);      // qkv bf16 (union ptmp fp32)
    float* ptmp   = (float*)qkvb;                                   // [6272,768] fp32
    bf16*  Vt     = (bf16*) alloc((long long)384 * 64 * 224 * 2);   // V transposed, padded
    bf16*  h1     = (bf16*) alloc((long long)NTOK * FFDIM * 2);     // FFN mid
    float* w2tmp  = (float*)alloc(2 * SZ * 4);                      // split-K partials
    bf16*  Ob     = (bf16*) alloc(SZ * 2);                          // attn out (union patches)
    bf16*  patches= Ob;
    bf16*  wqkv_t = (bf16*) alloc((long long)2304 * 768 * 2);
    bf16*  wo_t   = (bf16*) alloc((long long)768 * 768 * 2);
    bf16*  w1_t   = (bf16*) alloc((long long)3072 * 768 * 2);
    bf16*  w2_t   = (bf16*) alloc((long long)768 * 3072 * 2);
    bf16*  pw_t   = (bf16*) alloc((long long)768 * 768 * 2);
    float* bqkv   = (float*)alloc(2304 * 4);
    float* xcls   = (float*)alloc((long long)BATCHSZ * DMODEL * 4);

    // ---- embed ----
    extract_patches_k<<<dim3(BATCHSZ * NPATCH), dim3(256), 0, stream>>>(images, patches);
    transpose_conv_k<<<dim3(24, 24), dim3(256), 0, stream>>>(patch_W, pw_t, 768, 768);
    launch_mfma(stream, patches, pw_t, patch_b, nullptr, ptmp, nullptr,
                BATCHSZ * NPATCH, DMODEL, 768, DMODEL, 0, FLAG_BIAS);
    embed_k<<<dim3((int)(SZ / 256)), dim3(256), 0, stream>>>(ptmp, pos_emb, cls, x);

    const long long WQKV_L = (long long)NHEAD * DMODEL * HDIM;
    for (int l = 0; l < NLAYER; ++l) {
        conv_layer_k<<<dim3(6913), dim3(256), 0, stream>>>(
            Wq + (long long)l * WQKV_L, Wk + (long long)l * WQKV_L, Wv + (long long)l * WQKV_L,
            Wo + (long long)l * DMODEL * DMODEL,
            W1 + (long long)l * DMODEL * FFDIM,
            W2 + (long long)l * FFDIM * DMODEL,
            bq + (long long)l * 768, bk + (long long)l * 768, bv + (long long)l * 768,
            wqkv_t, wo_t, w1_t, w2_t, bqkv);

        // ln1 -> bf16
        ln_bf_k<<<dim3(NTOK), dim3(256), 0, stream>>>(
            x, DMODEL, ln1_g + l * DMODEL, ln1_b + l * DMODEL, xn, DMODEL);

        // fused QKV -> bf16 [6304][2304]
        launch_mfma(stream, xn, wqkv_t, bqkv, nullptr, nullptr, qkvb,
                    NTOK, 2304, DMODEL, 2304, 0, FLAG_BIAS | FLAG_OUTBF16);

        // V transpose
        vt_k<<<dim3(7, 2, 384), dim3(256), 0, stream>>>(qkvb, Vt);

        // fused MFMA attention -> Ob
        attn_k<<<dim3(4, 384), dim3(256), 0, stream>>>(qkvb, Vt, Ob);

        // x += Ob @ Wo + bo
        launch_mfma(stream, Ob, wo_t, bo + (long long)l * DMODEL, x, x, nullptr,
                    NTOK, DMODEL, DMODEL, DMODEL, DMODEL, FLAG_BIAS | FLAG_RESID);

        // ln2 -> bf16
        ln_bf_k<<<dim3(NTOK), dim3(256), 0, stream>>>(
            x, DMODEL, ln2_g + l * DMODEL, ln2_b + l * DMODEL, xn, DMODEL);

        // h1 = gelu(xn @ W1 + b1)
        launch_mfma(stream, xn, w1_t, b1 + (long long)l * FFDIM, nullptr, nullptr, h1,
                    NTOK, FFDIM, DMODEL, FFDIM, 0, FLAG_BIAS | FLAG_GELU | FLAG_OUTBF16);

        // W2 GEMM split-K (z=2, K=1536 each) -> w2tmp, then x += t0+t1+b2
        {
            dim3 grid(DMODEL / 128, (NTOK + 127) / 128, 2);
            mfma_gemm_k<<<grid, dim3(256), 0, stream>>>(
                h1, w2_t, nullptr, nullptr, w2tmp, nullptr,
                NTOK, DMODEL, 1536, FFDIM, FFDIM, DMODEL, 0,
                1536, 1536, SZ, 0);
            resid2_k<<<dim3((int)(SZ / 4 / 256)), dim3(256), 0, stream>>>(
                w2tmp, w2tmp + SZ, b2 + (long long)l * DMODEL, x);
        }
    }

    // ---- head ----
    ln_k<<<dim3(BATCHSZ), dim3(256), 0, stream>>>(
        x, (long long)S_LEN * DMODEL, head_g, head_bn, xcls, DMODEL);
    head_k<<<dim3(16, BATCHSZ), dim3(256), 0, stream>>>(xcls, head_W, head_bias, out);
}